// Round 1
// baseline (2945.464 us; speedup 1.0000x reference)
//
#include <hip/hip_runtime.h>

#define DD 128
#define WPAD 132   // pad to keep ds_read_b128 conflict-free & 16B-aligned
#define NSLOT 8

__global__ void deg_kernel(const int* __restrict__ dst, float* __restrict__ deg, int E) {
  int e = blockIdx.x * blockDim.x + threadIdx.x;
  if (e < E) atomicAdd(&deg[dst[e]], 1.0f);
}

// agg[dst[e]] += X[src[e]]  (float atomics, 4 floats/thread)
__global__ void scatter_kernel(const int* __restrict__ src, const int* __restrict__ dst,
                               const float* __restrict__ X, float* __restrict__ AGG, int E) {
  long long idx = (long long)blockIdx.x * blockDim.x + threadIdx.x;
  if (idx >= (long long)E * (DD / 4)) return;
  int e = (int)(idx >> 5);
  int q = ((int)idx & 31) * 4;
  int s = src[e], t = dst[e];
  const float4 v = *reinterpret_cast<const float4*>(X + (long long)s * DD + q);
  float* a = AGG + (long long)t * DD + q;
  atomicAdd(a + 0, v.x);
  atomicAdd(a + 1, v.y);
  atomicAdd(a + 2, v.z);
  atomicAdd(a + 3, v.w);
}

// H[n] = act( (A[n]/max(deg,1)) @ Wrel^T + X[n] @ Wroot^T + b )
// Both W^T matrices staged in LDS (140KB total). In-place H==A is safe:
// rows are staged into LDS before any write.
__global__ __launch_bounds__(256) void gemm_fused(
    const float* __restrict__ A, const float* __restrict__ deg,
    const float* __restrict__ X,
    const float* __restrict__ Wrel, const float* __restrict__ Wroot,
    const float* __restrict__ bias, float* __restrict__ H,
    int N, int npb, int do_relu) {
  __shared__ __align__(16) float WT[2][DD][WPAD];
  __shared__ float R[NSLOT][2][DD];
  int t = threadIdx.x;
  // load W transposed: WT[m][k][d] = W_m[d][k]; coalesced global reads
  for (int i = t; i < 2 * DD * DD; i += 256) {
    int m = i >> 14;
    int r = i & 16383;
    int d = r >> 7;
    int k = r & 127;
    const float* W = (m == 0) ? Wrel : Wroot;
    WT[m][k][d] = W[d * DD + k];
  }
  __syncthreads();

  int sl = t >> 5;          // node slot 0..7
  int q4 = (t & 31) * 4;    // output dims q4..q4+3
  float4 bb;
  bb.x = bias[q4 + 0]; bb.y = bias[q4 + 1]; bb.z = bias[q4 + 2]; bb.w = bias[q4 + 3];

  int base = blockIdx.x * npb;
  for (int n0 = base; n0 < base + npb && n0 < N; n0 += NSLOT) {
    // stage 8 nodes' (normalized agg row, x row) into LDS
    for (int i = t; i < NSLOT * 2 * DD; i += 256) {
      int slot = i >> 8;
      int which = (i >> 7) & 1;
      int d = i & 127;
      int node = n0 + slot;
      float v = 0.f;
      if (node < N) {
        if (which == 0) {
          float dg = deg[node];
          v = A[(long long)node * DD + d] / fmaxf(dg, 1.0f);
        } else {
          v = X[(long long)node * DD + d];
        }
      }
      R[slot][which][d] = v;
    }
    __syncthreads();

    float4 acc = bb;
    #pragma unroll 4
    for (int k = 0; k < DD; ++k) {
      float a0 = R[sl][0][k];
      float x0 = R[sl][1][k];
      float4 w0 = *reinterpret_cast<const float4*>(&WT[0][k][q4]);
      float4 w1 = *reinterpret_cast<const float4*>(&WT[1][k][q4]);
      acc.x += a0 * w0.x + x0 * w1.x;
      acc.y += a0 * w0.y + x0 * w1.y;
      acc.z += a0 * w0.z + x0 * w1.z;
      acc.w += a0 * w0.w + x0 * w1.w;
    }
    int node = n0 + sl;
    if (node < N) {
      if (do_relu) {
        acc.x = fmaxf(acc.x, 0.f); acc.y = fmaxf(acc.y, 0.f);
        acc.z = fmaxf(acc.z, 0.f); acc.w = fmaxf(acc.w, 0.f);
      }
      *reinterpret_cast<float4*>(&H[(long long)node * DD + q4]) = acc;
    }
    __syncthreads();
  }
}

__global__ void pool_sum(const float* __restrict__ H, const int* __restrict__ batch,
                         float* __restrict__ sums, int N) {
  long long idx = (long long)blockIdx.x * blockDim.x + threadIdx.x;
  if (idx >= (long long)N * (DD / 4)) return;
  int n = (int)(idx >> 5);
  int q = ((int)idx & 31) * 4;
  int g = batch[n];
  const float4 v = *reinterpret_cast<const float4*>(H + (long long)n * DD + q);
  float* s = sums + g * DD + q;
  atomicAdd(s + 0, v.x);
  atomicAdd(s + 1, v.y);
  atomicAdd(s + 2, v.z);
  atomicAdd(s + 3, v.w);
}

__global__ void pool_cnt(const int* __restrict__ batch, float* __restrict__ cnt, int N) {
  int n = blockIdx.x * blockDim.x + threadIdx.x;
  if (n < N) atomicAdd(&cnt[batch[n]], 1.0f);
}

__global__ void final_kernel(const float* __restrict__ sums, const float* __restrict__ cnt,
                             const float* __restrict__ Wc, const float* __restrict__ bc,
                             float* __restrict__ out, int G) {
  int g = blockIdx.x;
  int d = threadIdx.x;
  __shared__ float p[DD];
  float inv = 1.0f / fmaxf(cnt[g], 1.0f);
  p[d] = sums[g * DD + d] * inv;
  __syncthreads();
  float acc = bc[d];
  #pragma unroll 8
  for (int k = 0; k < DD; ++k) acc += p[k] * Wc[d * DD + k];
  out[g * DD + d] = acc;
}

extern "C" void kernel_launch(void* const* d_in, const int* in_sizes, int n_in,
                              void* d_out, int out_size, void* d_ws, size_t ws_size,
                              hipStream_t stream) {
  const float* x   = (const float*)d_in[0];
  const int*   ei  = (const int*)d_in[1];
  const int* batch = (const int*)d_in[2];
  const float* Wr1 = (const float*)d_in[3];
  const float* Wo1 = (const float*)d_in[4];
  const float* b1  = (const float*)d_in[5];
  const float* Wr2 = (const float*)d_in[6];
  const float* Wo2 = (const float*)d_in[7];
  const float* b2  = (const float*)d_in[8];
  const float* Wc  = (const float*)d_in[9];
  const float* bc  = (const float*)d_in[10];
  float* out = (float*)d_out;

  const int N = in_sizes[0] / DD;   // 40000
  const int E = in_sizes[1] / 2;    // 640000
  const int G = out_size / DD;      // 64
  const int* src = ei;
  const int* dst = ei + E;

  float* ws   = (float*)d_ws;
  float* deg  = ws;                                  // N floats (N%64==0 here)
  float* agg1 = deg + ((N + 63) & ~63);              // N*DD
  float* agg2 = agg1 + (size_t)N * DD;               // N*DD
  float* sums = agg2 + (size_t)N * DD;               // G*DD
  float* cnt  = sums + (size_t)G * DD;               // G
  size_t total_f = (size_t)(cnt + G - ws);
  hipMemsetAsync(d_ws, 0, total_f * sizeof(float), stream);

  const int blk = 256;
  deg_kernel<<<(E + blk - 1) / blk, blk, 0, stream>>>(dst, deg, E);

  long long sc_threads = (long long)E * (DD / 4);
  int sc_blocks = (int)((sc_threads + blk - 1) / blk);
  scatter_kernel<<<sc_blocks, blk, 0, stream>>>(src, dst, x, agg1, E);

  const int nblocks = 256;
  int npb = (((N + nblocks - 1) / nblocks) + NSLOT - 1) & ~(NSLOT - 1);
  gemm_fused<<<nblocks, 256, 0, stream>>>(agg1, deg, x, Wr1, Wo1, b1, agg1, N, npb, 1);

  scatter_kernel<<<sc_blocks, blk, 0, stream>>>(src, dst, agg1, agg2, E);
  gemm_fused<<<nblocks, 256, 0, stream>>>(agg2, deg, agg1, Wr2, Wo2, b2, agg2, N, npb, 1);

  long long pl_threads = (long long)N * (DD / 4);
  pool_sum<<<(int)((pl_threads + blk - 1) / blk), blk, 0, stream>>>(agg2, batch, sums, N);
  pool_cnt<<<(N + blk - 1) / blk, blk, 0, stream>>>(batch, cnt, N);
  final_kernel<<<G, DD, 0, stream>>>(sums, cnt, Wc, bc, out, G);
}

// Round 2
// 660.686 us; speedup vs baseline: 4.4582x; 4.4582x over previous
//
#include <hip/hip_runtime.h>

#define DD 128
#define GT 24          // gemm tile: nodes per block-iteration
#define ANODE 4        // agg: nodes per block (64 lanes each)

__global__ void deg_kernel(const int* __restrict__ dst, int* __restrict__ deg, int E) {
  int e = blockIdx.x * blockDim.x + threadIdx.x;
  if (e < E) atomicAdd(&deg[dst[e]], 1);
}

// single-block exclusive scan over N ints (N up to ~64K fine)
__global__ void scan_kernel(const int* __restrict__ deg, int* __restrict__ off, int N) {
  __shared__ int buf[1024];
  __shared__ int carry;
  if (threadIdx.x == 0) carry = 0;
  __syncthreads();
  for (int base = 0; base < N; base += 1024) {
    int i = base + threadIdx.x;
    int v = (i < N) ? deg[i] : 0;
    buf[threadIdx.x] = v;
    __syncthreads();
    for (int s = 1; s < 1024; s <<= 1) {
      int t = (threadIdx.x >= s) ? buf[threadIdx.x - s] : 0;
      __syncthreads();
      buf[threadIdx.x] += t;
      __syncthreads();
    }
    if (i < N) off[i] = carry + buf[threadIdx.x] - v;   // exclusive
    __syncthreads();
    if (threadIdx.x == 1023) carry += buf[1023];
    __syncthreads();
  }
  if (threadIdx.x == 0) off[N] = carry;
}

__global__ void fill_csr(const int* __restrict__ src, const int* __restrict__ dst,
                         const int* __restrict__ off, int* __restrict__ cursor,
                         int* __restrict__ csr, int E) {
  int e = blockIdx.x * blockDim.x + threadIdx.x;
  if (e < E) {
    int d = dst[e];
    int p = atomicAdd(&cursor[d], 1);
    csr[off[d] + p] = src[e];
  }
}

// AGG[n] = mean_{j in N(n)} X[j]   (gather, no atomics). 64 lanes per node, float2/lane.
__global__ __launch_bounds__(256) void agg_gather(
    const float* __restrict__ X, const int* __restrict__ csr,
    const int* __restrict__ off, const int* __restrict__ deg,
    float* __restrict__ AGG, int N) {
  int node = blockIdx.x * ANODE + (threadIdx.x >> 6);
  if (node >= N) return;
  int lane = threadIdx.x & 63;
  int p = off[node];
  int dg = deg[node];
  int pe = p + dg;
  float2 acc = make_float2(0.f, 0.f);
  for (; p + 4 <= pe; p += 4) {
    int s0 = csr[p], s1 = csr[p + 1], s2 = csr[p + 2], s3 = csr[p + 3];
    float2 v0 = *reinterpret_cast<const float2*>(X + (size_t)s0 * DD + lane * 2);
    float2 v1 = *reinterpret_cast<const float2*>(X + (size_t)s1 * DD + lane * 2);
    float2 v2 = *reinterpret_cast<const float2*>(X + (size_t)s2 * DD + lane * 2);
    float2 v3 = *reinterpret_cast<const float2*>(X + (size_t)s3 * DD + lane * 2);
    acc.x += (v0.x + v1.x) + (v2.x + v3.x);
    acc.y += (v0.y + v1.y) + (v2.y + v3.y);
  }
  for (; p < pe; ++p) {
    int s0 = csr[p];
    float2 v0 = *reinterpret_cast<const float2*>(X + (size_t)s0 * DD + lane * 2);
    acc.x += v0.x; acc.y += v0.y;
  }
  float inv = 1.f / fmaxf((float)dg, 1.f);
  acc.x *= inv; acc.y *= inv;
  *reinterpret_cast<float2*>(AGG + (size_t)node * DD + lane * 2) = acc;
}

// H[n] = act( A[n] @ Wrel^T + X[n] @ Wroot^T + b ), A already mean-normalized.
// Both W^T resident in LDS (k-major, padded); 3 nodes x 4 dims per thread.
__global__ __launch_bounds__(256) void gemm_fused(
    const float* __restrict__ A, const float* __restrict__ X,
    const float* __restrict__ Wrel, const float* __restrict__ Wroot,
    const float* __restrict__ bias, float* __restrict__ H,
    int N, int npb, int do_relu) {
  __shared__ __align__(16) float WT[2][DD][132];   // 135168 B, WT[m][k][d]
  __shared__ __align__(16) float Za[GT][132];      // 12672 B
  __shared__ __align__(16) float Zx[GT][132];      // 12672 B   (total 160512 <= 163840)
  int t = threadIdx.x;
  for (int i = t; i < 2 * DD * DD; i += 256) {
    int m = i >> 14, r = i & 16383, d = r >> 7, k = r & 127;
    WT[m][k][d] = (m ? Wroot : Wrel)[d * DD + k];
  }
  int tx = t & 31;          // dims d = tx*4 .. tx*4+3
  int ty = t >> 5;          // nodes n_loc = ty*3 .. ty*3+2
  int n_loc = ty * 3;
  float4 bb = *reinterpret_cast<const float4*>(bias + tx * 4);
  __syncthreads();

  int base = blockIdx.x * npb;
  int end = (base + npb < N) ? base + npb : N;
  for (int n0 = base; n0 < end; n0 += GT) {
    // stage GT nodes' A and X rows (float4 granularity)
    #pragma unroll
    for (int i = t; i < GT * 64; i += 256) {
      int sl = i >> 6;
      int iq = i & 63;
      int node = n0 + sl;
      float4 v = make_float4(0.f, 0.f, 0.f, 0.f);
      if (node < N) {
        if (iq < 32) v = *reinterpret_cast<const float4*>(A + (size_t)node * DD + iq * 4);
        else         v = *reinterpret_cast<const float4*>(X + (size_t)node * DD + (iq - 32) * 4);
      }
      if (iq < 32) *reinterpret_cast<float4*>(&Za[sl][iq * 4]) = v;
      else         *reinterpret_cast<float4*>(&Zx[sl][(iq - 32) * 4]) = v;
    }
    __syncthreads();

    float4 acc0 = bb, acc1 = bb, acc2 = bb;
    #pragma unroll 2
    for (int k = 0; k < DD; k += 4) {
      float4 za0 = *reinterpret_cast<const float4*>(&Za[n_loc][k]);
      float4 zx0 = *reinterpret_cast<const float4*>(&Zx[n_loc][k]);
      float4 za1 = *reinterpret_cast<const float4*>(&Za[n_loc + 1][k]);
      float4 zx1 = *reinterpret_cast<const float4*>(&Zx[n_loc + 1][k]);
      float4 za2 = *reinterpret_cast<const float4*>(&Za[n_loc + 2][k]);
      float4 zx2 = *reinterpret_cast<const float4*>(&Zx[n_loc + 2][k]);
      #pragma unroll
      for (int j = 0; j < 4; ++j) {
        float4 w0 = *reinterpret_cast<const float4*>(&WT[0][k + j][tx * 4]);
        float4 w1 = *reinterpret_cast<const float4*>(&WT[1][k + j][tx * 4]);
        float a0 = reinterpret_cast<const float*>(&za0)[j];
        float x0 = reinterpret_cast<const float*>(&zx0)[j];
        float a1 = reinterpret_cast<const float*>(&za1)[j];
        float x1 = reinterpret_cast<const float*>(&zx1)[j];
        float a2 = reinterpret_cast<const float*>(&za2)[j];
        float x2 = reinterpret_cast<const float*>(&zx2)[j];
        acc0.x += a0 * w0.x + x0 * w1.x;  acc0.y += a0 * w0.y + x0 * w1.y;
        acc0.z += a0 * w0.z + x0 * w1.z;  acc0.w += a0 * w0.w + x0 * w1.w;
        acc1.x += a1 * w0.x + x1 * w1.x;  acc1.y += a1 * w0.y + x1 * w1.y;
        acc1.z += a1 * w0.z + x1 * w1.z;  acc1.w += a1 * w0.w + x1 * w1.w;
        acc2.x += a2 * w0.x + x2 * w1.x;  acc2.y += a2 * w0.y + x2 * w1.y;
        acc2.z += a2 * w0.z + x2 * w1.z;  acc2.w += a2 * w0.w + x2 * w1.w;
      }
    }
    #pragma unroll
    for (int j = 0; j < 3; ++j) {
      int node = n0 + n_loc + j;
      if (node < N) {
        float4 acc = (j == 0) ? acc0 : (j == 1) ? acc1 : acc2;
        if (do_relu) {
          acc.x = fmaxf(acc.x, 0.f); acc.y = fmaxf(acc.y, 0.f);
          acc.z = fmaxf(acc.z, 0.f); acc.w = fmaxf(acc.w, 0.f);
        }
        *reinterpret_cast<float4*>(&H[(size_t)node * DD + tx * 4]) = acc;
      }
    }
    __syncthreads();
  }
}

// batch is sorted: per-block running segment sums, few atomics
__global__ void pool_kernel(const float* __restrict__ H, const int* __restrict__ batch,
                            float* __restrict__ sums, int N, int npb) {
  int d = threadIdx.x;                       // 128 threads = dims
  int n0 = blockIdx.x * npb;
  if (n0 >= N) return;
  int n1 = (n0 + npb < N) ? n0 + npb : N;
  float acc = 0.f;
  int g = batch[n0];
  for (int n = n0; n < n1; ++n) {
    int gn = batch[n];
    if (gn != g) { atomicAdd(&sums[g * DD + d], acc); acc = 0.f; g = gn; }
    acc += H[(size_t)n * DD + d];
  }
  atomicAdd(&sums[g * DD + d], acc);
}

__global__ void pool_cnt(const int* __restrict__ batch, float* __restrict__ cnt, int N) {
  int n = blockIdx.x * blockDim.x + threadIdx.x;
  if (n < N) atomicAdd(&cnt[batch[n]], 1.0f);
}

__global__ void final_kernel(const float* __restrict__ sums, const float* __restrict__ cnt,
                             const float* __restrict__ Wc, const float* __restrict__ bc,
                             float* __restrict__ out, int G) {
  int g = blockIdx.x;
  int d = threadIdx.x;
  __shared__ float p[DD];
  float inv = 1.0f / fmaxf(cnt[g], 1.0f);
  p[d] = sums[g * DD + d] * inv;
  __syncthreads();
  float acc = bc[d];
  #pragma unroll 8
  for (int k = 0; k < DD; ++k) acc += p[k] * Wc[d * DD + k];
  out[g * DD + d] = acc;
}

extern "C" void kernel_launch(void* const* d_in, const int* in_sizes, int n_in,
                              void* d_out, int out_size, void* d_ws, size_t ws_size,
                              hipStream_t stream) {
  const float* x   = (const float*)d_in[0];
  const int*   ei  = (const int*)d_in[1];
  const int* batch = (const int*)d_in[2];
  const float* Wr1 = (const float*)d_in[3];
  const float* Wo1 = (const float*)d_in[4];
  const float* b1  = (const float*)d_in[5];
  const float* Wr2 = (const float*)d_in[6];
  const float* Wo2 = (const float*)d_in[7];
  const float* b2  = (const float*)d_in[8];
  const float* Wc  = (const float*)d_in[9];
  const float* bc  = (const float*)d_in[10];
  float* out = (float*)d_out;

  const int N = in_sizes[0] / DD;   // 40000
  const int E = in_sizes[1] / 2;    // 640000
  const int G = out_size / DD;      // 64
  const int* src = ei;
  const int* dst = ei + E;

  const int Npad = (N + 64) & ~63;  // >= N+1, 16-int aligned
  int* iws    = (int*)d_ws;
  int* deg    = iws;                // Npad
  int* cursor = deg + Npad;         // Npad
  int* off    = cursor + Npad;      // Npad
  int* csr    = off + Npad;         // E
  float* sums = (float*)(csr + E);  // G*DD
  float* cnt  = sums + (size_t)G * DD;        // G (pad to 64)
  float* agg1 = cnt + 64;                     // N*DD
  float* agg2 = agg1 + (size_t)N * DD;        // N*DD

  // zero: deg+cursor, sums+cnt
  hipMemsetAsync(deg, 0, (size_t)2 * Npad * sizeof(int), stream);
  hipMemsetAsync(sums, 0, ((size_t)G * DD + 64) * sizeof(float), stream);

  const int blk = 256;
  deg_kernel<<<(E + blk - 1) / blk, blk, 0, stream>>>(dst, deg, E);
  scan_kernel<<<1, 1024, 0, stream>>>(deg, off, N);
  fill_csr<<<(E + blk - 1) / blk, blk, 0, stream>>>(src, dst, off, cursor, csr, E);

  int agg_blocks = (N + ANODE - 1) / ANODE;
  const int nblocks = 256;
  int npb = ((((N + nblocks - 1) / nblocks) + GT - 1) / GT) * GT;

  // layer 1
  agg_gather<<<agg_blocks, 256, 0, stream>>>(x, csr, off, deg, agg1, N);
  gemm_fused<<<nblocks, 256, 0, stream>>>(agg1, x, Wr1, Wo1, b1, agg1, N, npb, 1);
  // layer 2
  agg_gather<<<agg_blocks, 256, 0, stream>>>(agg1, csr, off, deg, agg2, N);
  gemm_fused<<<nblocks, 256, 0, stream>>>(agg2, agg1, Wr2, Wo2, b2, agg2, N, npb, 1);

  // pool + classify
  int pool_npb = 64;
  pool_kernel<<<(N + pool_npb - 1) / pool_npb, DD, 0, stream>>>(agg2, batch, sums, N, pool_npb);
  pool_cnt<<<(N + blk - 1) / blk, blk, 0, stream>>>(batch, cnt, N);
  final_kernel<<<G, DD, 0, stream>>>(sums, cnt, Wc, bc, out, G);
}

// Round 3
// 362.296 us; speedup vs baseline: 8.1300x; 1.8236x over previous
//
#include <hip/hip_runtime.h>

#define DD 128
#define GT 24          // gemm tile: nodes per block-iteration
#define ANODE 4        // agg: nodes per block (64 lanes each)

__global__ void deg_kernel(const int* __restrict__ dst, int* __restrict__ deg, int E) {
  int e = blockIdx.x * blockDim.x + threadIdx.x;
  if (e < E) atomicAdd(&deg[dst[e]], 1);
}

// ---- parallel exclusive scan of deg -> off (3 kernels) ----
__global__ void block_sum(const int* __restrict__ deg, int* __restrict__ part, int N) {
  int base = blockIdx.x * 1024;
  int s = 0;
  for (int i = threadIdx.x; i < 1024; i += 256) {
    int idx = base + i;
    s += (idx < N) ? deg[idx] : 0;
  }
  for (int o = 32; o; o >>= 1) s += __shfl_down(s, o, 64);
  __shared__ int ws[4];
  if ((threadIdx.x & 63) == 0) ws[threadIdx.x >> 6] = s;
  __syncthreads();
  if (threadIdx.x == 0) part[blockIdx.x] = ws[0] + ws[1] + ws[2] + ws[3];
}

__global__ void scan_part(int* __restrict__ part, int* __restrict__ total, int nb) {
  __shared__ int buf[256];
  int v = (threadIdx.x < nb) ? part[threadIdx.x] : 0;
  buf[threadIdx.x] = v;
  __syncthreads();
  for (int s = 1; s < 256; s <<= 1) {
    int t = (threadIdx.x >= s) ? buf[threadIdx.x - s] : 0;
    __syncthreads();
    buf[threadIdx.x] += t;
    __syncthreads();
  }
  if (threadIdx.x < nb) part[threadIdx.x] = buf[threadIdx.x] - v;  // exclusive
  if (threadIdx.x == 255) *total = buf[255];
}

__global__ void off_kernel(const int* __restrict__ deg, const int* __restrict__ part,
                           const int* __restrict__ total, int* __restrict__ off, int N) {
  __shared__ int buf[1024];
  int i = blockIdx.x * 1024 + threadIdx.x;
  int v = (i < N) ? deg[i] : 0;
  buf[threadIdx.x] = v;
  __syncthreads();
  for (int s = 1; s < 1024; s <<= 1) {
    int t = (threadIdx.x >= s) ? buf[threadIdx.x - s] : 0;
    __syncthreads();
    buf[threadIdx.x] += t;
    __syncthreads();
  }
  if (i < N) off[i] = part[blockIdx.x] + buf[threadIdx.x] - v;
  if (blockIdx.x == 0 && threadIdx.x == 0) off[N] = *total;
}

__global__ void fill_csr(const int* __restrict__ src, const int* __restrict__ dst,
                         const int* __restrict__ off, int* __restrict__ cursor,
                         int* __restrict__ csr, int E) {
  int e = blockIdx.x * blockDim.x + threadIdx.x;
  if (e < E) {
    int d = dst[e];
    int p = atomicAdd(&cursor[d], 1);
    csr[off[d] + p] = src[e];
  }
}

// AGG[n] = mean_{j in N(n)} X[j]   (gather, no atomics). 64 lanes per node, float2/lane.
__global__ __launch_bounds__(256) void agg_gather(
    const float* __restrict__ X, const int* __restrict__ csr,
    const int* __restrict__ off, const int* __restrict__ deg,
    float* __restrict__ AGG, int N) {
  int node = blockIdx.x * ANODE + (threadIdx.x >> 6);
  if (node >= N) return;
  int lane = threadIdx.x & 63;
  int p = off[node];
  int dg = deg[node];
  int pe = p + dg;
  float2 acc = make_float2(0.f, 0.f);
  for (; p + 4 <= pe; p += 4) {
    int s0 = csr[p], s1 = csr[p + 1], s2 = csr[p + 2], s3 = csr[p + 3];
    float2 v0 = *reinterpret_cast<const float2*>(X + (size_t)s0 * DD + lane * 2);
    float2 v1 = *reinterpret_cast<const float2*>(X + (size_t)s1 * DD + lane * 2);
    float2 v2 = *reinterpret_cast<const float2*>(X + (size_t)s2 * DD + lane * 2);
    float2 v3 = *reinterpret_cast<const float2*>(X + (size_t)s3 * DD + lane * 2);
    acc.x += (v0.x + v1.x) + (v2.x + v3.x);
    acc.y += (v0.y + v1.y) + (v2.y + v3.y);
  }
  for (; p < pe; ++p) {
    int s0 = csr[p];
    float2 v0 = *reinterpret_cast<const float2*>(X + (size_t)s0 * DD + lane * 2);
    acc.x += v0.x; acc.y += v0.y;
  }
  float inv = 1.f / fmaxf((float)dg, 1.f);
  acc.x *= inv; acc.y *= inv;
  *reinterpret_cast<float2*>(AGG + (size_t)node * DD + lane * 2) = acc;
}

// H[n] = act( A[n] @ Wrel^T + X[n] @ Wroot^T + b ), A already mean-normalized.
__global__ __launch_bounds__(256) void gemm_fused(
    const float* __restrict__ A, const float* __restrict__ X,
    const float* __restrict__ Wrel, const float* __restrict__ Wroot,
    const float* __restrict__ bias, float* __restrict__ H,
    int N, int npb, int do_relu) {
  __shared__ __align__(16) float WT[2][DD][132];   // 135168 B, WT[m][k][d]
  __shared__ __align__(16) float Za[GT][132];      // 12672 B
  __shared__ __align__(16) float Zx[GT][132];      // 12672 B   (total 160512 <= 163840)
  int t = threadIdx.x;
  for (int i = t; i < 2 * DD * DD; i += 256) {
    int m = i >> 14, r = i & 16383, d = r >> 7, k = r & 127;
    WT[m][k][d] = (m ? Wroot : Wrel)[d * DD + k];
  }
  int tx = t & 31;          // dims d = tx*4 .. tx*4+3
  int ty = t >> 5;          // nodes n_loc = ty*3 .. ty*3+2
  int n_loc = ty * 3;
  float4 bb = *reinterpret_cast<const float4*>(bias + tx * 4);
  __syncthreads();

  int base = blockIdx.x * npb;
  int end = (base + npb < N) ? base + npb : N;
  for (int n0 = base; n0 < end; n0 += GT) {
    #pragma unroll
    for (int i = t; i < GT * 64; i += 256) {
      int sl = i >> 6;
      int iq = i & 63;
      int node = n0 + sl;
      float4 v = make_float4(0.f, 0.f, 0.f, 0.f);
      if (node < N) {
        if (iq < 32) v = *reinterpret_cast<const float4*>(A + (size_t)node * DD + iq * 4);
        else         v = *reinterpret_cast<const float4*>(X + (size_t)node * DD + (iq - 32) * 4);
      }
      if (iq < 32) *reinterpret_cast<float4*>(&Za[sl][iq * 4]) = v;
      else         *reinterpret_cast<float4*>(&Zx[sl][(iq - 32) * 4]) = v;
    }
    __syncthreads();

    float4 acc0 = bb, acc1 = bb, acc2 = bb;
    #pragma unroll 2
    for (int k = 0; k < DD; k += 4) {
      float4 za0 = *reinterpret_cast<const float4*>(&Za[n_loc][k]);
      float4 zx0 = *reinterpret_cast<const float4*>(&Zx[n_loc][k]);
      float4 za1 = *reinterpret_cast<const float4*>(&Za[n_loc + 1][k]);
      float4 zx1 = *reinterpret_cast<const float4*>(&Zx[n_loc + 1][k]);
      float4 za2 = *reinterpret_cast<const float4*>(&Za[n_loc + 2][k]);
      float4 zx2 = *reinterpret_cast<const float4*>(&Zx[n_loc + 2][k]);
      #pragma unroll
      for (int j = 0; j < 4; ++j) {
        float4 w0 = *reinterpret_cast<const float4*>(&WT[0][k + j][tx * 4]);
        float4 w1 = *reinterpret_cast<const float4*>(&WT[1][k + j][tx * 4]);
        float a0 = reinterpret_cast<const float*>(&za0)[j];
        float x0 = reinterpret_cast<const float*>(&zx0)[j];
        float a1 = reinterpret_cast<const float*>(&za1)[j];
        float x1 = reinterpret_cast<const float*>(&zx1)[j];
        float a2 = reinterpret_cast<const float*>(&za2)[j];
        float x2 = reinterpret_cast<const float*>(&zx2)[j];
        acc0.x += a0 * w0.x + x0 * w1.x;  acc0.y += a0 * w0.y + x0 * w1.y;
        acc0.z += a0 * w0.z + x0 * w1.z;  acc0.w += a0 * w0.w + x0 * w1.w;
        acc1.x += a1 * w0.x + x1 * w1.x;  acc1.y += a1 * w0.y + x1 * w1.y;
        acc1.z += a1 * w0.z + x1 * w1.z;  acc1.w += a1 * w0.w + x1 * w1.w;
        acc2.x += a2 * w0.x + x2 * w1.x;  acc2.y += a2 * w0.y + x2 * w1.y;
        acc2.z += a2 * w0.z + x2 * w1.z;  acc2.w += a2 * w0.w + x2 * w1.w;
      }
    }
    #pragma unroll
    for (int j = 0; j < 3; ++j) {
      int node = n0 + n_loc + j;
      if (node < N) {
        float4 acc = (j == 0) ? acc0 : (j == 1) ? acc1 : acc2;
        if (do_relu) {
          acc.x = fmaxf(acc.x, 0.f); acc.y = fmaxf(acc.y, 0.f);
          acc.z = fmaxf(acc.z, 0.f); acc.w = fmaxf(acc.w, 0.f);
        }
        *reinterpret_cast<float4*>(&H[(size_t)node * DD + tx * 4]) = acc;
      }
    }
    __syncthreads();
  }
}

// batch is sorted: per-block running segment sums, few atomics
__global__ void pool_kernel(const float* __restrict__ H, const int* __restrict__ batch,
                            float* __restrict__ sums, int N, int npb) {
  int d = threadIdx.x;                       // 128 threads = dims
  int n0 = blockIdx.x * npb;
  if (n0 >= N) return;
  int n1 = (n0 + npb < N) ? n0 + npb : N;
  float acc = 0.f;
  int g = batch[n0];
  for (int n = n0; n < n1; ++n) {
    int gn = batch[n];
    if (gn != g) { atomicAdd(&sums[g * DD + d], acc); acc = 0.f; g = gn; }
    acc += H[(size_t)n * DD + d];
  }
  atomicAdd(&sums[g * DD + d], acc);
}

// batch sorted -> cnt[g] = lb(g+1) - lb(g), binary search, no atomics
__global__ void cnt_kernel(const int* __restrict__ batch, float* __restrict__ cnt,
                           int N, int G) {
  int g = blockIdx.x * blockDim.x + threadIdx.x;
  if (g >= G) return;
  int lo = 0, hi = N;
  while (lo < hi) { int m = (lo + hi) >> 1; if (batch[m] < g) lo = m + 1; else hi = m; }
  int a = lo;
  lo = 0; hi = N;
  while (lo < hi) { int m = (lo + hi) >> 1; if (batch[m] < g + 1) lo = m + 1; else hi = m; }
  cnt[g] = (float)(lo - a);
}

__global__ void final_kernel(const float* __restrict__ sums, const float* __restrict__ cnt,
                             const float* __restrict__ Wc, const float* __restrict__ bc,
                             float* __restrict__ out, int G) {
  int g = blockIdx.x;
  int d = threadIdx.x;
  __shared__ float p[DD];
  float inv = 1.0f / fmaxf(cnt[g], 1.0f);
  p[d] = sums[g * DD + d] * inv;
  __syncthreads();
  float acc = bc[d];
  #pragma unroll 8
  for (int k = 0; k < DD; ++k) acc += p[k] * Wc[d * DD + k];
  out[g * DD + d] = acc;
}

extern "C" void kernel_launch(void* const* d_in, const int* in_sizes, int n_in,
                              void* d_out, int out_size, void* d_ws, size_t ws_size,
                              hipStream_t stream) {
  const float* x   = (const float*)d_in[0];
  const int*   ei  = (const int*)d_in[1];
  const int* batch = (const int*)d_in[2];
  const float* Wr1 = (const float*)d_in[3];
  const float* Wo1 = (const float*)d_in[4];
  const float* b1  = (const float*)d_in[5];
  const float* Wr2 = (const float*)d_in[6];
  const float* Wo2 = (const float*)d_in[7];
  const float* b2  = (const float*)d_in[8];
  const float* Wc  = (const float*)d_in[9];
  const float* bc  = (const float*)d_in[10];
  float* out = (float*)d_out;

  const int N = in_sizes[0] / DD;   // 40000
  const int E = in_sizes[1] / 2;    // 640000
  const int G = out_size / DD;      // 64
  const int* src = ei;
  const int* dst = ei + E;

  const int Npad = (N + 64) & ~63;  // >= N+1, 16-int aligned
  const int NB1024 = (N + 1023) / 1024;
  int* iws    = (int*)d_ws;
  int* deg    = iws;                // Npad
  int* cursor = deg + Npad;         // Npad
  int* off    = cursor + Npad;      // Npad
  int* part   = off + Npad;         // NB1024 (+1 for total)
  int* total  = part + ((NB1024 + 64) & ~63);
  int* csr    = total + 64;         // E
  float* sums = (float*)(csr + E);  // G*DD
  float* cnt  = sums + (size_t)G * DD;        // G (pad to 64)
  float* agg1 = cnt + 64;                     // N*DD
  float* agg2 = agg1 + (size_t)N * DD;        // N*DD

  hipMemsetAsync(deg, 0, (size_t)2 * Npad * sizeof(int), stream);
  hipMemsetAsync(sums, 0, (size_t)G * DD * sizeof(float), stream);

  const int blk = 256;
  deg_kernel<<<(E + blk - 1) / blk, blk, 0, stream>>>(dst, deg, E);
  block_sum<<<NB1024, 256, 0, stream>>>(deg, part, N);
  scan_part<<<1, 256, 0, stream>>>(part, total, NB1024);
  off_kernel<<<NB1024, 1024, 0, stream>>>(deg, part, total, off, N);
  fill_csr<<<(E + blk - 1) / blk, blk, 0, stream>>>(src, dst, off, cursor, csr, E);

  int agg_blocks = (N + ANODE - 1) / ANODE;
  const int nblocks = 256;
  int npb = ((((N + nblocks - 1) / nblocks) + GT - 1) / GT) * GT;

  // layer 1
  agg_gather<<<agg_blocks, 256, 0, stream>>>(x, csr, off, deg, agg1, N);
  gemm_fused<<<nblocks, 256, 0, stream>>>(agg1, x, Wr1, Wo1, b1, agg1, N, npb, 1);
  // layer 2
  agg_gather<<<agg_blocks, 256, 0, stream>>>(agg1, csr, off, deg, agg2, N);
  gemm_fused<<<nblocks, 256, 0, stream>>>(agg2, agg1, Wr2, Wo2, b2, agg2, N, npb, 1);

  // pool + classify
  int pool_npb = 64;
  pool_kernel<<<(N + pool_npb - 1) / pool_npb, DD, 0, stream>>>(agg2, batch, sums, N, pool_npb);
  cnt_kernel<<<1, 64, 0, stream>>>(batch, cnt, N, G);
  final_kernel<<<G, DD, 0, stream>>>(sums, cnt, Wc, bc, out, G);
}

// Round 4
// 299.337 us; speedup vs baseline: 9.8400x; 1.2103x over previous
//
#include <hip/hip_runtime.h>

#define DD 128
#define BM 64          // gemm: nodes per block
#define ANODE 4        // agg: nodes per block (64 lanes each)

__global__ void deg_kernel(const int* __restrict__ dst, int* __restrict__ deg, int E) {
  int e = blockIdx.x * blockDim.x + threadIdx.x;
  if (e < E) atomicAdd(&deg[dst[e]], 1);
}

// ---- parallel exclusive scan of deg -> off ----
__global__ void block_sum(const int* __restrict__ deg, int* __restrict__ part, int N) {
  int base = blockIdx.x * 1024;
  int s = 0;
  for (int i = threadIdx.x; i < 1024; i += 256) {
    int idx = base + i;
    s += (idx < N) ? deg[idx] : 0;
  }
  for (int o = 32; o; o >>= 1) s += __shfl_down(s, o, 64);
  __shared__ int ws[4];
  if ((threadIdx.x & 63) == 0) ws[threadIdx.x >> 6] = s;
  __syncthreads();
  if (threadIdx.x == 0) part[blockIdx.x] = ws[0] + ws[1] + ws[2] + ws[3];
}

__global__ void scan_part(int* __restrict__ part, int* __restrict__ total, int nb) {
  __shared__ int buf[256];
  int v = (threadIdx.x < nb) ? part[threadIdx.x] : 0;
  buf[threadIdx.x] = v;
  __syncthreads();
  for (int s = 1; s < 256; s <<= 1) {
    int t = (threadIdx.x >= s) ? buf[threadIdx.x - s] : 0;
    __syncthreads();
    buf[threadIdx.x] += t;
    __syncthreads();
  }
  if (threadIdx.x < nb) part[threadIdx.x] = buf[threadIdx.x] - v;  // exclusive
  if (threadIdx.x == 255) *total = buf[255];
}

__global__ void off_kernel(const int* __restrict__ deg, const int* __restrict__ part,
                           const int* __restrict__ total, int* __restrict__ off, int N) {
  __shared__ int buf[1024];
  int i = blockIdx.x * 1024 + threadIdx.x;
  int v = (i < N) ? deg[i] : 0;
  buf[threadIdx.x] = v;
  __syncthreads();
  for (int s = 1; s < 1024; s <<= 1) {
    int t = (threadIdx.x >= s) ? buf[threadIdx.x - s] : 0;
    __syncthreads();
    buf[threadIdx.x] += t;
    __syncthreads();
  }
  if (i < N) off[i] = part[blockIdx.x] + buf[threadIdx.x] - v;
  if (blockIdx.x == 0 && threadIdx.x == 0) off[N] = *total;
}

__global__ void fill_csr(const int* __restrict__ src, const int* __restrict__ dst,
                         const int* __restrict__ off, int* __restrict__ cursor,
                         int* __restrict__ csr, int E) {
  int e = blockIdx.x * blockDim.x + threadIdx.x;
  if (e < E) {
    int d = dst[e];
    int p = atomicAdd(&cursor[d], 1);
    csr[off[d] + p] = src[e];
  }
}

// transpose 4 128x128 matrices: Wt[k][d] = W[d][k]
__global__ void wt_kernel(const float* __restrict__ W0, const float* __restrict__ W1,
                          const float* __restrict__ W2, const float* __restrict__ W3,
                          float* __restrict__ T0, float* __restrict__ T1,
                          float* __restrict__ T2, float* __restrict__ T3) {
  __shared__ float tile[32][33];
  int m = blockIdx.x >> 4;
  int tidx = blockIdx.x & 15;
  int bx = tidx & 3, by = tidx >> 2;
  const float* W = (m == 0) ? W0 : (m == 1) ? W1 : (m == 2) ? W2 : W3;
  float* T = (m == 0) ? T0 : (m == 1) ? T1 : (m == 2) ? T2 : T3;
  int lx = threadIdx.x & 31, ly = threadIdx.x >> 5;
  #pragma unroll
  for (int j = 0; j < 32; j += 8)
    tile[ly + j][lx] = W[(by * 32 + ly + j) * DD + bx * 32 + lx];
  __syncthreads();
  #pragma unroll
  for (int j = 0; j < 32; j += 8)
    T[(bx * 32 + ly + j) * DD + by * 32 + lx] = tile[lx][ly + j];
}

// AGG[n] = mean_{j in N(n)} X[j]   (gather, no atomics). 64 lanes per node.
__global__ __launch_bounds__(256) void agg_gather(
    const float* __restrict__ X, const int* __restrict__ csr,
    const int* __restrict__ off, const int* __restrict__ deg,
    float* __restrict__ AGG, int N) {
  int node = blockIdx.x * ANODE + (threadIdx.x >> 6);
  if (node >= N) return;
  int lane = threadIdx.x & 63;
  int p = off[node];
  int dg = deg[node];
  int pe = p + dg;
  float2 acc = make_float2(0.f, 0.f);
  for (; p + 4 <= pe; p += 4) {
    int s0 = csr[p], s1 = csr[p + 1], s2 = csr[p + 2], s3 = csr[p + 3];
    float2 v0 = *reinterpret_cast<const float2*>(X + (size_t)s0 * DD + lane * 2);
    float2 v1 = *reinterpret_cast<const float2*>(X + (size_t)s1 * DD + lane * 2);
    float2 v2 = *reinterpret_cast<const float2*>(X + (size_t)s2 * DD + lane * 2);
    float2 v3 = *reinterpret_cast<const float2*>(X + (size_t)s3 * DD + lane * 2);
    acc.x += (v0.x + v1.x) + (v2.x + v3.x);
    acc.y += (v0.y + v1.y) + (v2.y + v3.y);
  }
  for (; p < pe; ++p) {
    int s0 = csr[p];
    float2 v0 = *reinterpret_cast<const float2*>(X + (size_t)s0 * DD + lane * 2);
    acc.x += v0.x; acc.y += v0.y;
  }
  float inv = 1.f / fmaxf((float)dg, 1.f);
  acc.x *= inv; acc.y *= inv;
  *reinterpret_cast<float2*>(AGG + (size_t)node * DD + lane * 2) = acc;
}

// H[n] = act( A[n] @ WtRel + X[n] @ WtRoot + b ), Wt pre-transposed [k][d].
// LDS = 32KB (one 64-node operand tile at a time) -> 5 blocks/CU.
// Thread (tx,ty): dims 4tx..4tx+3, nodes ty*8..ty*8+7. a-reads are half-wave
// broadcasts (no bank conflicts); w-reads are coalesced 512B rows from L2/L1.
__global__ __launch_bounds__(256) void gemm_v2(
    const float* __restrict__ A, const float* __restrict__ X,
    const float* __restrict__ WtRel, const float* __restrict__ WtRoot,
    const float* __restrict__ bias, float* __restrict__ H,
    int N, int do_relu) {
  __shared__ __align__(16) float Z[BM][DD];
  int t = threadIdx.x;
  int tx = t & 31, ty = t >> 5;
  int n0 = blockIdx.x * BM;
  float4 acc[8];
  #pragma unroll
  for (int j = 0; j < 8; ++j) acc[j] = make_float4(0.f, 0.f, 0.f, 0.f);

  #pragma unroll
  for (int ph = 0; ph < 2; ++ph) {
    const float* S  = ph ? X : A;
    const float* Wt = ph ? WtRoot : WtRel;
    // stage 64 rows x 128 floats (coalesced float4)
    #pragma unroll
    for (int i = t; i < BM * 32; i += 256) {
      int sl = i >> 5, q = i & 31;
      int node = n0 + sl;
      float4 v = (node < N) ? *reinterpret_cast<const float4*>(S + (size_t)node * DD + q * 4)
                            : make_float4(0.f, 0.f, 0.f, 0.f);
      *reinterpret_cast<float4*>(&Z[sl][q * 4]) = v;
    }
    __syncthreads();

    #pragma unroll 2
    for (int k = 0; k < DD; k += 4) {
      float4 w0 = *reinterpret_cast<const float4*>(Wt + (size_t)(k + 0) * DD + tx * 4);
      float4 w1 = *reinterpret_cast<const float4*>(Wt + (size_t)(k + 1) * DD + tx * 4);
      float4 w2 = *reinterpret_cast<const float4*>(Wt + (size_t)(k + 2) * DD + tx * 4);
      float4 w3 = *reinterpret_cast<const float4*>(Wt + (size_t)(k + 3) * DD + tx * 4);
      #pragma unroll
      for (int j = 0; j < 8; ++j) {
        float4 zv = *reinterpret_cast<const float4*>(&Z[ty * 8 + j][k]);
        acc[j].x += zv.x * w0.x + zv.y * w1.x + zv.z * w2.x + zv.w * w3.x;
        acc[j].y += zv.x * w0.y + zv.y * w1.y + zv.z * w2.y + zv.w * w3.y;
        acc[j].z += zv.x * w0.z + zv.y * w1.z + zv.z * w2.z + zv.w * w3.z;
        acc[j].w += zv.x * w0.w + zv.y * w1.w + zv.z * w2.w + zv.w * w3.w;
      }
    }
    __syncthreads();
  }

  float4 bb = *reinterpret_cast<const float4*>(bias + tx * 4);
  #pragma unroll
  for (int j = 0; j < 8; ++j) {
    int node = n0 + ty * 8 + j;
    if (node < N) {
      float4 a = acc[j];
      a.x += bb.x; a.y += bb.y; a.z += bb.z; a.w += bb.w;
      if (do_relu) {
        a.x = fmaxf(a.x, 0.f); a.y = fmaxf(a.y, 0.f);
        a.z = fmaxf(a.z, 0.f); a.w = fmaxf(a.w, 0.f);
      }
      *reinterpret_cast<float4*>(&H[(size_t)node * DD + tx * 4]) = a;
    }
  }
}

// batch is sorted: per-block running segment sums, few atomics
__global__ void pool_kernel(const float* __restrict__ H, const int* __restrict__ batch,
                            float* __restrict__ sums, int N, int npb) {
  int d = threadIdx.x;                       // 128 threads = dims
  int n0 = blockIdx.x * npb;
  if (n0 >= N) return;
  int n1 = (n0 + npb < N) ? n0 + npb : N;
  float acc = 0.f;
  int g = batch[n0];
  for (int n = n0; n < n1; ++n) {
    int gn = batch[n];
    if (gn != g) { atomicAdd(&sums[g * DD + d], acc); acc = 0.f; g = gn; }
    acc += H[(size_t)n * DD + d];
  }
  atomicAdd(&sums[g * DD + d], acc);
}

// batch sorted -> cnt[g] via binary search, no atomics
__global__ void cnt_kernel(const int* __restrict__ batch, float* __restrict__ cnt,
                           int N, int G) {
  int g = blockIdx.x * blockDim.x + threadIdx.x;
  if (g >= G) return;
  int lo = 0, hi = N;
  while (lo < hi) { int m = (lo + hi) >> 1; if (batch[m] < g) lo = m + 1; else hi = m; }
  int a = lo;
  lo = 0; hi = N;
  while (lo < hi) { int m = (lo + hi) >> 1; if (batch[m] < g + 1) lo = m + 1; else hi = m; }
  cnt[g] = (float)(lo - a);
}

__global__ void final_kernel(const float* __restrict__ sums, const float* __restrict__ cnt,
                             const float* __restrict__ Wc, const float* __restrict__ bc,
                             float* __restrict__ out, int G) {
  int g = blockIdx.x;
  int d = threadIdx.x;
  __shared__ float p[DD];
  float inv = 1.0f / fmaxf(cnt[g], 1.0f);
  p[d] = sums[g * DD + d] * inv;
  __syncthreads();
  float acc = bc[d];
  #pragma unroll 8
  for (int k = 0; k < DD; ++k) acc += p[k] * Wc[d * DD + k];
  out[g * DD + d] = acc;
}

extern "C" void kernel_launch(void* const* d_in, const int* in_sizes, int n_in,
                              void* d_out, int out_size, void* d_ws, size_t ws_size,
                              hipStream_t stream) {
  const float* x   = (const float*)d_in[0];
  const int*   ei  = (const int*)d_in[1];
  const int* batch = (const int*)d_in[2];
  const float* Wr1 = (const float*)d_in[3];
  const float* Wo1 = (const float*)d_in[4];
  const float* b1  = (const float*)d_in[5];
  const float* Wr2 = (const float*)d_in[6];
  const float* Wo2 = (const float*)d_in[7];
  const float* b2  = (const float*)d_in[8];
  const float* Wc  = (const float*)d_in[9];
  const float* bc  = (const float*)d_in[10];
  float* out = (float*)d_out;

  const int N = in_sizes[0] / DD;   // 40000
  const int E = in_sizes[1] / 2;    // 640000
  const int G = out_size / DD;      // 64
  const int* src = ei;
  const int* dst = ei + E;

  const int Npad = (N + 64) & ~63;  // >= N+1, 16-int aligned
  const int NB1024 = (N + 1023) / 1024;
  int* iws    = (int*)d_ws;
  int* deg    = iws;                // Npad
  int* cursor = deg + Npad;         // Npad
  int* off    = cursor + Npad;      // Npad
  int* part   = off + Npad;         // NB1024 (+pad)
  int* total  = part + ((NB1024 + 64) & ~63);
  int* csr    = total + 64;         // E
  float* sums = (float*)(csr + E);  // G*DD
  float* cnt  = sums + (size_t)G * DD;        // 64
  float* wt1r = cnt + 64;                     // 4x 128*128 transposed weights
  float* wt1o = wt1r + DD * DD;
  float* wt2r = wt1o + DD * DD;
  float* wt2o = wt2r + DD * DD;
  float* agg1 = wt2o + DD * DD;               // N*DD
  float* agg2 = agg1 + (size_t)N * DD;        // N*DD

  hipMemsetAsync(deg, 0, (size_t)2 * Npad * sizeof(int), stream);
  hipMemsetAsync(sums, 0, (size_t)G * DD * sizeof(float), stream);

  const int blk = 256;
  deg_kernel<<<(E + blk - 1) / blk, blk, 0, stream>>>(dst, deg, E);
  block_sum<<<NB1024, 256, 0, stream>>>(deg, part, N);
  scan_part<<<1, 256, 0, stream>>>(part, total, NB1024);
  off_kernel<<<NB1024, 1024, 0, stream>>>(deg, part, total, off, N);
  fill_csr<<<(E + blk - 1) / blk, blk, 0, stream>>>(src, dst, off, cursor, csr, E);
  wt_kernel<<<64, 256, 0, stream>>>(Wr1, Wo1, Wr2, Wo2, wt1r, wt1o, wt2r, wt2o);

  int agg_blocks = (N + ANODE - 1) / ANODE;
  int gemm_blocks = (N + BM - 1) / BM;

  // layer 1
  agg_gather<<<agg_blocks, 256, 0, stream>>>(x, csr, off, deg, agg1, N);
  gemm_v2<<<gemm_blocks, 256, 0, stream>>>(agg1, x, wt1r, wt1o, b1, agg1, N, 1);
  // layer 2
  agg_gather<<<agg_blocks, 256, 0, stream>>>(agg1, csr, off, deg, agg2, N);
  gemm_v2<<<gemm_blocks, 256, 0, stream>>>(agg2, agg1, wt2r, wt2o, b2, agg2, N, 1);

  // pool + classify
  int pool_npb = 64;
  pool_kernel<<<(N + pool_npb - 1) / pool_npb, DD, 0, stream>>>(agg2, batch, sums, N, pool_npb);
  cnt_kernel<<<1, 64, 0, stream>>>(batch, cnt, N, G);
  final_kernel<<<G, DD, 0, stream>>>(sums, cnt, Wc, bc, out, G);
}

// Round 5
// 290.102 us; speedup vs baseline: 10.1532x; 1.0318x over previous
//
#include <hip/hip_runtime.h>

#define DD 128
#define BM 32          // gemm: nodes per block
#define ANODE 4        // agg: nodes per block (64 lanes each)

static __device__ __forceinline__ unsigned short f2bf(float f) {
  unsigned int u = __float_as_uint(f);
  u = (u + 0x7fffu + ((u >> 16) & 1u)) >> 16;   // RNE
  return (unsigned short)u;
}

__global__ void deg_kernel(const int* __restrict__ dst, int* __restrict__ deg, int E) {
  int e = blockIdx.x * blockDim.x + threadIdx.x;
  if (e < E) atomicAdd(&deg[dst[e]], 1);
}

// ---- parallel exclusive scan of deg -> off ----
__global__ void block_sum(const int* __restrict__ deg, int* __restrict__ part, int N) {
  int base = blockIdx.x * 1024;
  int s = 0;
  for (int i = threadIdx.x; i < 1024; i += 256) {
    int idx = base + i;
    s += (idx < N) ? deg[idx] : 0;
  }
  for (int o = 32; o; o >>= 1) s += __shfl_down(s, o, 64);
  __shared__ int ws[4];
  if ((threadIdx.x & 63) == 0) ws[threadIdx.x >> 6] = s;
  __syncthreads();
  if (threadIdx.x == 0) part[blockIdx.x] = ws[0] + ws[1] + ws[2] + ws[3];
}

__global__ void scan_part(int* __restrict__ part, int* __restrict__ total, int nb) {
  __shared__ int buf[256];
  int v = (threadIdx.x < nb) ? part[threadIdx.x] : 0;
  buf[threadIdx.x] = v;
  __syncthreads();
  for (int s = 1; s < 256; s <<= 1) {
    int t = (threadIdx.x >= s) ? buf[threadIdx.x - s] : 0;
    __syncthreads();
    buf[threadIdx.x] += t;
    __syncthreads();
  }
  if (threadIdx.x < nb) part[threadIdx.x] = buf[threadIdx.x] - v;  // exclusive
  if (threadIdx.x == 255) *total = buf[255];
}

__global__ void off_kernel(const int* __restrict__ deg, const int* __restrict__ part,
                           const int* __restrict__ total, int* __restrict__ off, int N) {
  __shared__ int buf[1024];
  int i = blockIdx.x * 1024 + threadIdx.x;
  int v = (i < N) ? deg[i] : 0;
  buf[threadIdx.x] = v;
  __syncthreads();
  for (int s = 1; s < 1024; s <<= 1) {
    int t = (threadIdx.x >= s) ? buf[threadIdx.x - s] : 0;
    __syncthreads();
    buf[threadIdx.x] += t;
    __syncthreads();
  }
  if (i < N) off[i] = part[blockIdx.x] + buf[threadIdx.x] - v;
  if (blockIdx.x == 0 && threadIdx.x == 0) off[N] = *total;
}

__global__ void fill_csr(const int* __restrict__ src, const int* __restrict__ dst,
                         const int* __restrict__ off, int* __restrict__ cursor,
                         int* __restrict__ csr, int E) {
  int e = blockIdx.x * blockDim.x + threadIdx.x;
  if (e < E) {
    int d = dst[e];
    int p = atomicAdd(&cursor[d], 1);
    csr[off[d] + p] = src[e];
  }
}

// transpose 4 128x128 matrices: Wt[k][d] = W[d][k]
__global__ void wt_kernel(const float* __restrict__ W0, const float* __restrict__ W1,
                          const float* __restrict__ W2, const float* __restrict__ W3,
                          float* __restrict__ T0, float* __restrict__ T1,
                          float* __restrict__ T2, float* __restrict__ T3) {
  __shared__ float tile[32][33];
  int m = blockIdx.x >> 4;
  int tidx = blockIdx.x & 15;
  int bx = tidx & 3, by = tidx >> 2;
  const float* W = (m == 0) ? W0 : (m == 1) ? W1 : (m == 2) ? W2 : W3;
  float* T = (m == 0) ? T0 : (m == 1) ? T1 : (m == 2) ? T2 : T3;
  int lx = threadIdx.x & 31, ly = threadIdx.x >> 5;
  #pragma unroll
  for (int j = 0; j < 32; j += 8)
    tile[ly + j][lx] = W[(by * 32 + ly + j) * DD + bx * 32 + lx];
  __syncthreads();
  #pragma unroll
  for (int j = 0; j < 32; j += 8)
    T[(bx * 32 + ly + j) * DD + by * 32 + lx] = tile[lx][ly + j];
}

// fp32 -> bf16 (4 elems/thread)
__global__ void tobf16_kernel(const float* __restrict__ in, unsigned short* __restrict__ outp,
                              int n4) {
  int i = blockIdx.x * blockDim.x + threadIdx.x;
  if (i >= n4) return;
  float4 v = reinterpret_cast<const float4*>(in)[i];
  ushort4 o;
  o.x = f2bf(v.x); o.y = f2bf(v.y); o.z = f2bf(v.z); o.w = f2bf(v.w);
  reinterpret_cast<ushort4*>(outp)[i] = o;
}

// AGG[n] = mean_{j in N(n)} Xh[j]  — bf16 rows (256B/row), fp32 accumulate.
__global__ __launch_bounds__(256) void agg_gather_bf16(
    const unsigned int* __restrict__ Xh, const int* __restrict__ csr,
    const int* __restrict__ off, const int* __restrict__ deg,
    float* __restrict__ AGG, int N) {
  int node = blockIdx.x * ANODE + (threadIdx.x >> 6);
  if (node >= N) return;
  int lane = threadIdx.x & 63;
  int p = off[node];
  int dg = deg[node];
  int pe = p + dg;
  float2 acc = make_float2(0.f, 0.f);
  for (; p + 4 <= pe; p += 4) {
    int s0 = csr[p], s1 = csr[p + 1], s2 = csr[p + 2], s3 = csr[p + 3];
    unsigned int u0 = Xh[(size_t)s0 * 64 + lane];
    unsigned int u1 = Xh[(size_t)s1 * 64 + lane];
    unsigned int u2 = Xh[(size_t)s2 * 64 + lane];
    unsigned int u3 = Xh[(size_t)s3 * 64 + lane];
    acc.x += __uint_as_float(u0 << 16) + __uint_as_float(u1 << 16)
           + __uint_as_float(u2 << 16) + __uint_as_float(u3 << 16);
    acc.y += __uint_as_float(u0 & 0xffff0000u) + __uint_as_float(u1 & 0xffff0000u)
           + __uint_as_float(u2 & 0xffff0000u) + __uint_as_float(u3 & 0xffff0000u);
  }
  for (; p < pe; ++p) {
    unsigned int u0 = Xh[(size_t)csr[p] * 64 + lane];
    acc.x += __uint_as_float(u0 << 16);
    acc.y += __uint_as_float(u0 & 0xffff0000u);
  }
  float inv = 1.f / fmaxf((float)dg, 1.f);
  acc.x *= inv; acc.y *= inv;
  *reinterpret_cast<float2*>(AGG + (size_t)node * DD + lane * 2) = acc;
}

// fp32 fallback gather (round-4 proven)
__global__ __launch_bounds__(256) void agg_gather_f32(
    const float* __restrict__ X, const int* __restrict__ csr,
    const int* __restrict__ off, const int* __restrict__ deg,
    float* __restrict__ AGG, int N) {
  int node = blockIdx.x * ANODE + (threadIdx.x >> 6);
  if (node >= N) return;
  int lane = threadIdx.x & 63;
  int p = off[node];
  int dg = deg[node];
  int pe = p + dg;
  float2 acc = make_float2(0.f, 0.f);
  for (; p + 4 <= pe; p += 4) {
    int s0 = csr[p], s1 = csr[p + 1], s2 = csr[p + 2], s3 = csr[p + 3];
    float2 v0 = *reinterpret_cast<const float2*>(X + (size_t)s0 * DD + lane * 2);
    float2 v1 = *reinterpret_cast<const float2*>(X + (size_t)s1 * DD + lane * 2);
    float2 v2 = *reinterpret_cast<const float2*>(X + (size_t)s2 * DD + lane * 2);
    float2 v3 = *reinterpret_cast<const float2*>(X + (size_t)s3 * DD + lane * 2);
    acc.x += (v0.x + v1.x) + (v2.x + v3.x);
    acc.y += (v0.y + v1.y) + (v2.y + v3.y);
  }
  for (; p < pe; ++p) {
    float2 v0 = *reinterpret_cast<const float2*>(X + (size_t)csr[p] * DD + lane * 2);
    acc.x += v0.x; acc.y += v0.y;
  }
  float inv = 1.f / fmaxf((float)dg, 1.f);
  acc.x *= inv; acc.y *= inv;
  *reinterpret_cast<float2*>(AGG + (size_t)node * DD + lane * 2) = acc;
}

// H[n] = act( A[n] @ WtRel + X[n] @ WtRoot + b ); 32-node tile, 16KB LDS.
// Optionally also emits bf16 copy (for next layer's gather).
__global__ __launch_bounds__(256) void gemm_v3(
    const float* __restrict__ A, const float* __restrict__ X,
    const float* __restrict__ WtRel, const float* __restrict__ WtRoot,
    const float* __restrict__ bias, float* __restrict__ H,
    unsigned short* __restrict__ Hb, int N, int do_relu) {
  __shared__ __align__(16) float Z[BM][DD];
  int t = threadIdx.x;
  int tx = t & 31, ty = t >> 5;
  int n0 = blockIdx.x * BM;
  float4 acc[4];
  #pragma unroll
  for (int j = 0; j < 4; ++j) acc[j] = make_float4(0.f, 0.f, 0.f, 0.f);

  #pragma unroll
  for (int ph = 0; ph < 2; ++ph) {
    const float* S  = ph ? X : A;
    const float* Wt = ph ? WtRoot : WtRel;
    #pragma unroll
    for (int i = t; i < BM * 32; i += 256) {
      int sl = i >> 5, q = i & 31;
      int node = n0 + sl;
      float4 v = (node < N) ? *reinterpret_cast<const float4*>(S + (size_t)node * DD + q * 4)
                            : make_float4(0.f, 0.f, 0.f, 0.f);
      *reinterpret_cast<float4*>(&Z[sl][q * 4]) = v;
    }
    __syncthreads();

    #pragma unroll 2
    for (int k = 0; k < DD; k += 4) {
      float4 w0 = *reinterpret_cast<const float4*>(Wt + (size_t)(k + 0) * DD + tx * 4);
      float4 w1 = *reinterpret_cast<const float4*>(Wt + (size_t)(k + 1) * DD + tx * 4);
      float4 w2 = *reinterpret_cast<const float4*>(Wt + (size_t)(k + 2) * DD + tx * 4);
      float4 w3 = *reinterpret_cast<const float4*>(Wt + (size_t)(k + 3) * DD + tx * 4);
      #pragma unroll
      for (int j = 0; j < 4; ++j) {
        float4 zv = *reinterpret_cast<const float4*>(&Z[ty * 4 + j][k]);
        acc[j].x += zv.x * w0.x + zv.y * w1.x + zv.z * w2.x + zv.w * w3.x;
        acc[j].y += zv.x * w0.y + zv.y * w1.y + zv.z * w2.y + zv.w * w3.y;
        acc[j].z += zv.x * w0.z + zv.y * w1.z + zv.z * w2.z + zv.w * w3.z;
        acc[j].w += zv.x * w0.w + zv.y * w1.w + zv.z * w2.w + zv.w * w3.w;
      }
    }
    __syncthreads();
  }

  float4 bb = *reinterpret_cast<const float4*>(bias + tx * 4);
  #pragma unroll
  for (int j = 0; j < 4; ++j) {
    int node = n0 + ty * 4 + j;
    if (node < N) {
      float4 a = acc[j];
      a.x += bb.x; a.y += bb.y; a.z += bb.z; a.w += bb.w;
      if (do_relu) {
        a.x = fmaxf(a.x, 0.f); a.y = fmaxf(a.y, 0.f);
        a.z = fmaxf(a.z, 0.f); a.w = fmaxf(a.w, 0.f);
      }
      *reinterpret_cast<float4*>(&H[(size_t)node * DD + tx * 4]) = a;
      if (Hb) {
        ushort4 o;
        o.x = f2bf(a.x); o.y = f2bf(a.y); o.z = f2bf(a.z); o.w = f2bf(a.w);
        *reinterpret_cast<ushort4*>(Hb + (size_t)node * DD + tx * 4) = o;
      }
    }
  }
}

// batch is sorted: per-block running segment sums, few atomics
__global__ void pool_kernel(const float* __restrict__ H, const int* __restrict__ batch,
                            float* __restrict__ sums, int N, int npb) {
  int d = threadIdx.x;
  int n0 = blockIdx.x * npb;
  if (n0 >= N) return;
  int n1 = (n0 + npb < N) ? n0 + npb : N;
  float acc = 0.f;
  int g = batch[n0];
  for (int n = n0; n < n1; ++n) {
    int gn = batch[n];
    if (gn != g) { atomicAdd(&sums[g * DD + d], acc); acc = 0.f; g = gn; }
    acc += H[(size_t)n * DD + d];
  }
  atomicAdd(&sums[g * DD + d], acc);
}

__global__ void cnt_kernel(const int* __restrict__ batch, float* __restrict__ cnt,
                           int N, int G) {
  int g = blockIdx.x * blockDim.x + threadIdx.x;
  if (g >= G) return;
  int lo = 0, hi = N;
  while (lo < hi) { int m = (lo + hi) >> 1; if (batch[m] < g) lo = m + 1; else hi = m; }
  int a = lo;
  lo = 0; hi = N;
  while (lo < hi) { int m = (lo + hi) >> 1; if (batch[m] < g + 1) lo = m + 1; else hi = m; }
  cnt[g] = (float)(lo - a);
}

__global__ void final_kernel(const float* __restrict__ sums, const float* __restrict__ cnt,
                             const float* __restrict__ Wc, const float* __restrict__ bc,
                             float* __restrict__ out, int G) {
  int g = blockIdx.x;
  int d = threadIdx.x;
  __shared__ float p[DD];
  float inv = 1.0f / fmaxf(cnt[g], 1.0f);
  p[d] = sums[g * DD + d] * inv;
  __syncthreads();
  float acc = bc[d];
  #pragma unroll 8
  for (int k = 0; k < DD; ++k) acc += p[k] * Wc[d * DD + k];
  out[g * DD + d] = acc;
}

extern "C" void kernel_launch(void* const* d_in, const int* in_sizes, int n_in,
                              void* d_out, int out_size, void* d_ws, size_t ws_size,
                              hipStream_t stream) {
  const float* x   = (const float*)d_in[0];
  const int*   ei  = (const int*)d_in[1];
  const int* batch = (const int*)d_in[2];
  const float* Wr1 = (const float*)d_in[3];
  const float* Wo1 = (const float*)d_in[4];
  const float* b1  = (const float*)d_in[5];
  const float* Wr2 = (const float*)d_in[6];
  const float* Wo2 = (const float*)d_in[7];
  const float* b2  = (const float*)d_in[8];
  const float* Wc  = (const float*)d_in[9];
  const float* bc  = (const float*)d_in[10];
  float* out = (float*)d_out;

  const int N = in_sizes[0] / DD;   // 40000
  const int E = in_sizes[1] / 2;    // 640000
  const int G = out_size / DD;      // 64
  const int* src = ei;
  const int* dst = ei + E;

  const int Npad = (N + 64) & ~63;
  const int NB1024 = (N + 1023) / 1024;
  int* iws    = (int*)d_ws;
  int* deg    = iws;                // Npad
  int* cursor = deg + Npad;         // Npad
  int* off    = cursor + Npad;      // Npad
  int* part   = off + Npad;
  int* total  = part + ((NB1024 + 64) & ~63);
  int* csr    = total + 64;         // E
  float* sums = (float*)(csr + E);  // G*DD
  float* cnt  = sums + (size_t)G * DD;        // 64
  float* wt1r = cnt + 64;
  float* wt1o = wt1r + DD * DD;
  float* wt2r = wt1o + DD * DD;
  float* wt2o = wt2r + DD * DD;
  float* agg1 = wt2o + DD * DD;               // N*DD
  float* agg2 = agg1 + (size_t)N * DD;        // N*DD
  unsigned short* xh = (unsigned short*)(agg2 + (size_t)N * DD);  // N*DD bf16 (reused for h1)
  size_t need = (size_t)((char*)(xh + (size_t)N * DD) - (char*)d_ws);
  int use_bf16 = (ws_size >= need);

  hipMemsetAsync(deg, 0, (size_t)2 * Npad * sizeof(int), stream);
  hipMemsetAsync(sums, 0, (size_t)G * DD * sizeof(float), stream);

  const int blk = 256;
  deg_kernel<<<(E + blk - 1) / blk, blk, 0, stream>>>(dst, deg, E);
  block_sum<<<NB1024, 256, 0, stream>>>(deg, part, N);
  scan_part<<<1, 256, 0, stream>>>(part, total, NB1024);
  off_kernel<<<NB1024, 1024, 0, stream>>>(deg, part, total, off, N);
  fill_csr<<<(E + blk - 1) / blk, blk, 0, stream>>>(src, dst, off, cursor, csr, E);
  wt_kernel<<<64, 256, 0, stream>>>(Wr1, Wo1, Wr2, Wo2, wt1r, wt1o, wt2r, wt2o);

  int agg_blocks = (N + ANODE - 1) / ANODE;
  int gemm_blocks = (N + BM - 1) / BM;
  int pool_npb = 64;

  if (use_bf16) {
    int n4 = N * DD / 4;
    tobf16_kernel<<<(n4 + blk - 1) / blk, blk, 0, stream>>>(x, xh, n4);
    // layer 1
    agg_gather_bf16<<<agg_blocks, 256, 0, stream>>>((const unsigned int*)xh, csr, off, deg, agg1, N);
    gemm_v3<<<gemm_blocks, 256, 0, stream>>>(agg1, x, wt1r, wt1o, b1, agg1, xh, N, 1);  // h1 fp32 + bf16
    // layer 2
    agg_gather_bf16<<<agg_blocks, 256, 0, stream>>>((const unsigned int*)xh, csr, off, deg, agg2, N);
    gemm_v3<<<gemm_blocks, 256, 0, stream>>>(agg2, agg1, wt2r, wt2o, b2, agg2, nullptr, N, 1);
  } else {
    agg_gather_f32<<<agg_blocks, 256, 0, stream>>>(x, csr, off, deg, agg1, N);
    gemm_v3<<<gemm_blocks, 256, 0, stream>>>(agg1, x, wt1r, wt1o, b1, agg1, nullptr, N, 1);
    agg_gather_f32<<<agg_blocks, 256, 0, stream>>>(agg1, csr, off, deg, agg2, N);
    gemm_v3<<<gemm_blocks, 256, 0, stream>>>(agg2, agg1, wt2r, wt2o, b2, agg2, nullptr, N, 1);
  }

  pool_kernel<<<(N + pool_npb - 1) / pool_npb, DD, 0, stream>>>(agg2, batch, sums, N, pool_npb);
  cnt_kernel<<<1, 64, 0, stream>>>(batch, cnt, N, G);
  final_kernel<<<G, DD, 0, stream>>>(sums, cnt, Wc, bc, out, G);
}

// Round 6
// 217.140 us; speedup vs baseline: 13.5648x; 1.3360x over previous
//
#include <hip/hip_runtime.h>

#define DD 128
#define ANODE 4        // gather: nodes per block (64 lanes each)

typedef __attribute__((ext_vector_type(8))) short short8v;
typedef __attribute__((ext_vector_type(4))) float float4v;

static __device__ __forceinline__ unsigned short f2bf(float f) {
  unsigned int u = __float_as_uint(f);
  u = (u + 0x7fffu + ((u >> 16) & 1u)) >> 16;   // RNE
  return (unsigned short)u;
}
static __device__ __forceinline__ float bf2f(unsigned short h) {
  return __uint_as_float(((unsigned int)h) << 16);
}

__global__ void deg_kernel(const int* __restrict__ dst, int* __restrict__ deg, int E) {
  int e = blockIdx.x * blockDim.x + threadIdx.x;
  if (e < E) atomicAdd(&deg[dst[e]], 1);
}

// ---- parallel exclusive scan of deg -> off ----
__global__ void block_sum(const int* __restrict__ deg, int* __restrict__ part, int N) {
  int base = blockIdx.x * 1024;
  int s = 0;
  for (int i = threadIdx.x; i < 1024; i += 256) {
    int idx = base + i;
    s += (idx < N) ? deg[idx] : 0;
  }
  for (int o = 32; o; o >>= 1) s += __shfl_down(s, o, 64);
  __shared__ int ws[4];
  if ((threadIdx.x & 63) == 0) ws[threadIdx.x >> 6] = s;
  __syncthreads();
  if (threadIdx.x == 0) part[blockIdx.x] = ws[0] + ws[1] + ws[2] + ws[3];
}

__global__ void scan_part(int* __restrict__ part, int* __restrict__ total, int nb) {
  __shared__ int buf[256];
  int v = (threadIdx.x < nb) ? part[threadIdx.x] : 0;
  buf[threadIdx.x] = v;
  __syncthreads();
  for (int s = 1; s < 256; s <<= 1) {
    int t = (threadIdx.x >= s) ? buf[threadIdx.x - s] : 0;
    __syncthreads();
    buf[threadIdx.x] += t;
    __syncthreads();
  }
  if (threadIdx.x < nb) part[threadIdx.x] = buf[threadIdx.x] - v;  // exclusive
  if (threadIdx.x == 255) *total = buf[255];
}

__global__ void off_kernel(const int* __restrict__ deg, const int* __restrict__ part,
                           const int* __restrict__ total, int* __restrict__ off, int N) {
  __shared__ int buf[1024];
  int i = blockIdx.x * 1024 + threadIdx.x;
  int v = (i < N) ? deg[i] : 0;
  buf[threadIdx.x] = v;
  __syncthreads();
  for (int s = 1; s < 1024; s <<= 1) {
    int t = (threadIdx.x >= s) ? buf[threadIdx.x - s] : 0;
    __syncthreads();
    buf[threadIdx.x] += t;
    __syncthreads();
  }
  if (i < N) off[i] = part[blockIdx.x] + buf[threadIdx.x] - v;
  if (blockIdx.x == 0 && threadIdx.x == 0) off[N] = *total;
}

__global__ void fill_csr(const int* __restrict__ src, const int* __restrict__ dst,
                         const int* __restrict__ off, int* __restrict__ cursor,
                         int* __restrict__ csr, int E) {
  int e = blockIdx.x * blockDim.x + threadIdx.x;
  if (e < E) {
    int d = dst[e];
    int p = atomicAdd(&cursor[d], 1);
    csr[off[d] + p] = src[e];
  }
}

// Pack W into MFMA B-fragment layout (bf16).
// Bpk[((L*64 + kt*8 + nt)*64 + lane)*8 + j] = Wt[kt*32+(lane>>4)*8+j][nt*16+(lane&15)]
// where Wt[k][d] = (k<128 ? Wrel[d][k] : Wroot[d][k-128]) for layer L.
__global__ void wpack_kernel(const float* __restrict__ Wr1, const float* __restrict__ Wo1,
                             const float* __restrict__ Wr2, const float* __restrict__ Wo2,
                             unsigned short* __restrict__ Bpk) {
  int tid = blockIdx.x * blockDim.x + threadIdx.x;   // 8192 threads
  if (tid >= 8192) return;
  int L = tid >> 12;
  int rest = tid & 4095;
  int kt = rest >> 9;
  int nt = (rest >> 6) & 7;
  int lane = rest & 63;
  int d = nt * 16 + (lane & 15);
  int kbase = kt * 32 + (lane >> 4) * 8;
  const float* Wrel = L ? Wr2 : Wr1;
  const float* Wroot = L ? Wo2 : Wo1;
  unsigned short* o = Bpk + ((size_t)tid) * 8;
  #pragma unroll
  for (int j = 0; j < 8; ++j) {
    int k = kbase + j;
    float w = (k < DD) ? Wrel[d * DD + k] : Wroot[d * DD + (k - DD)];
    o[j] = f2bf(w);
  }
}

// x (fp32) -> XHL rows: [hi(128) | lo(128)] bf16 (or hi only if AS==128)
__global__ void xsplit_kernel(const float* __restrict__ in, unsigned short* __restrict__ outp,
                              int N, int AS, int has_lo) {
  int i = blockIdx.x * blockDim.x + threadIdx.x;   // N*32 threads, 4 elems each
  if (i >= N * 32) return;
  int row = i >> 5, q = i & 31;
  float4 v = reinterpret_cast<const float4*>(in)[(size_t)row * 32 + q];
  ushort4 h; ushort4 l;
  h.x = f2bf(v.x); h.y = f2bf(v.y); h.z = f2bf(v.z); h.w = f2bf(v.w);
  *reinterpret_cast<ushort4*>(outp + (size_t)row * AS + q * 4) = h;
  if (has_lo) {
    l.x = f2bf(v.x - bf2f(h.x)); l.y = f2bf(v.y - bf2f(h.y));
    l.z = f2bf(v.z - bf2f(h.z)); l.w = f2bf(v.w - bf2f(h.w));
    *reinterpret_cast<ushort4*>(outp + (size_t)row * AS + DD + q * 4) = l;
  }
}

// AGG[n] = mean_{j in N(n)} X[j] reading hi-bf16 rows; emits hi/lo bf16.
__global__ __launch_bounds__(256) void gather_hl(
    const unsigned short* __restrict__ XHL, const int* __restrict__ csr,
    const int* __restrict__ off, const int* __restrict__ deg,
    unsigned short* __restrict__ AHL, int N, int AS, int has_lo) {
  int node = blockIdx.x * ANODE + (threadIdx.x >> 6);
  if (node >= N) return;
  int lane = threadIdx.x & 63;
  int p = off[node];
  int dg = deg[node];
  int pe = p + dg;
  int rs = AS >> 1;                                  // row stride in u32
  const unsigned int* X32 = (const unsigned int*)XHL;
  float2 acc = make_float2(0.f, 0.f);
  for (; p + 4 <= pe; p += 4) {
    int s0 = csr[p], s1 = csr[p + 1], s2 = csr[p + 2], s3 = csr[p + 3];
    unsigned int u0 = X32[(size_t)s0 * rs + lane];
    unsigned int u1 = X32[(size_t)s1 * rs + lane];
    unsigned int u2 = X32[(size_t)s2 * rs + lane];
    unsigned int u3 = X32[(size_t)s3 * rs + lane];
    acc.x += __uint_as_float(u0 << 16) + __uint_as_float(u1 << 16)
           + __uint_as_float(u2 << 16) + __uint_as_float(u3 << 16);
    acc.y += __uint_as_float(u0 & 0xffff0000u) + __uint_as_float(u1 & 0xffff0000u)
           + __uint_as_float(u2 & 0xffff0000u) + __uint_as_float(u3 & 0xffff0000u);
  }
  for (; p < pe; ++p) {
    unsigned int u0 = X32[(size_t)csr[p] * rs + lane];
    acc.x += __uint_as_float(u0 << 16);
    acc.y += __uint_as_float(u0 & 0xffff0000u);
  }
  float inv = 1.f / fmaxf((float)dg, 1.f);
  float vx = acc.x * inv, vy = acc.y * inv;
  unsigned short hx = f2bf(vx), hy = f2bf(vy);
  *reinterpret_cast<ushort2*>(AHL + (size_t)node * AS + lane * 2) = make_ushort2(hx, hy);
  if (has_lo) {
    unsigned short lx = f2bf(vx - bf2f(hx)), ly = f2bf(vy - bf2f(hy));
    *reinterpret_cast<ushort2*>(AHL + (size_t)node * AS + DD + lane * 2) = make_ushort2(lx, ly);
  }
}

// H = relu( [A|X](N x 256) @ Wcat(256 x 128) + b ) via MFMA, split-activation fp32 fidelity.
// One 16-row tile per wave; K=256 = 8 kt of 32; 8 nt col-tiles.
__global__ __launch_bounds__(256) void gemm_mfma(
    const unsigned short* __restrict__ AHL, const unsigned short* __restrict__ XHL,
    const unsigned short* __restrict__ Bpk, const float* __restrict__ bias,
    float* __restrict__ Hf, unsigned short* __restrict__ Hhl,
    int N, int AS, int has_lo, int do_relu) {
  int lane = threadIdx.x & 63;
  int wid = threadIdx.x >> 6;
  int m0 = (blockIdx.x * 4 + wid) * 16;
  if (m0 >= N) return;
  int arow = m0 + (lane & 15);
  int koff = (lane >> 4) * 8;
  const short8v* Bf = (const short8v*)Bpk;
  float4v acc[8];
  #pragma unroll
  for (int nt = 0; nt < 8; ++nt) acc[nt] = (float4v){0.f, 0.f, 0.f, 0.f};

  #pragma unroll
  for (int kt = 0; kt < 8; ++kt) {
    const unsigned short* base = (kt < 4)
        ? (AHL + (size_t)arow * AS + kt * 32 + koff)
        : (XHL + (size_t)arow * AS + (kt - 4) * 32 + koff);
    short8v ahi = *reinterpret_cast<const short8v*>(base);
    if (has_lo) {
      short8v alo = *reinterpret_cast<const short8v*>(base + DD);
      #pragma unroll
      for (int nt = 0; nt < 8; ++nt) {
        short8v b = Bf[(kt * 8 + nt) * 64 + lane];
        acc[nt] = __builtin_amdgcn_mfma_f32_16x16x32_bf16(ahi, b, acc[nt], 0, 0, 0);
        acc[nt] = __builtin_amdgcn_mfma_f32_16x16x32_bf16(alo, b, acc[nt], 0, 0, 0);
      }
    } else {
      #pragma unroll
      for (int nt = 0; nt < 8; ++nt) {
        short8v b = Bf[(kt * 8 + nt) * 64 + lane];
        acc[nt] = __builtin_amdgcn_mfma_f32_16x16x32_bf16(ahi, b, acc[nt], 0, 0, 0);
      }
    }
  }

  // D[row=(lane>>4)*4+r][col=nt*16+(lane&15)]
  int col0 = lane & 15;
  int rbase = m0 + (lane >> 4) * 4;
  #pragma unroll
  for (int nt = 0; nt < 8; ++nt) {
    int col = nt * 16 + col0;
    float bv = bias[col];
    #pragma unroll
    for (int r = 0; r < 4; ++r) {
      float v = acc[nt][r] + bv;
      if (do_relu) v = fmaxf(v, 0.f);
      size_t orow = (size_t)(rbase + r);
      if (Hf) Hf[orow * DD + col] = v;
      if (Hhl) {
        unsigned short h = f2bf(v);
        Hhl[orow * AS + col] = h;
        if (has_lo) Hhl[orow * AS + DD + col] = f2bf(v - bf2f(h));
      }
    }
  }
}

// batch is sorted: per-block running segment sums, few atomics
__global__ void pool_kernel(const float* __restrict__ H, const int* __restrict__ batch,
                            float* __restrict__ sums, int N, int npb) {
  int d = threadIdx.x;
  int n0 = blockIdx.x * npb;
  if (n0 >= N) return;
  int n1 = (n0 + npb < N) ? n0 + npb : N;
  float acc = 0.f;
  int g = batch[n0];
  for (int n = n0; n < n1; ++n) {
    int gn = batch[n];
    if (gn != g) { atomicAdd(&sums[g * DD + d], acc); acc = 0.f; g = gn; }
    acc += H[(size_t)n * DD + d];
  }
  atomicAdd(&sums[g * DD + d], acc);
}

__global__ void cnt_kernel(const int* __restrict__ batch, float* __restrict__ cnt,
                           int N, int G) {
  int g = blockIdx.x * blockDim.x + threadIdx.x;
  if (g >= G) return;
  int lo = 0, hi = N;
  while (lo < hi) { int m = (lo + hi) >> 1; if (batch[m] < g) lo = m + 1; else hi = m; }
  int a = lo;
  lo = 0; hi = N;
  while (lo < hi) { int m = (lo + hi) >> 1; if (batch[m] < g + 1) lo = m + 1; else hi = m; }
  cnt[g] = (float)(lo - a);
}

__global__ void final_kernel(const float* __restrict__ sums, const float* __restrict__ cnt,
                             const float* __restrict__ Wc, const float* __restrict__ bc,
                             float* __restrict__ out, int G) {
  int g = blockIdx.x;
  int d = threadIdx.x;
  __shared__ float p[DD];
  float inv = 1.0f / fmaxf(cnt[g], 1.0f);
  p[d] = sums[g * DD + d] * inv;
  __syncthreads();
  float acc = bc[d];
  #pragma unroll 8
  for (int k = 0; k < DD; ++k) acc += p[k] * Wc[d * DD + k];
  out[g * DD + d] = acc;
}

extern "C" void kernel_launch(void* const* d_in, const int* in_sizes, int n_in,
                              void* d_out, int out_size, void* d_ws, size_t ws_size,
                              hipStream_t stream) {
  const float* x   = (const float*)d_in[0];
  const int*   ei  = (const int*)d_in[1];
  const int* batch = (const int*)d_in[2];
  const float* Wr1 = (const float*)d_in[3];
  const float* Wo1 = (const float*)d_in[4];
  const float* b1  = (const float*)d_in[5];
  const float* Wr2 = (const float*)d_in[6];
  const float* Wo2 = (const float*)d_in[7];
  const float* b2  = (const float*)d_in[8];
  const float* Wc  = (const float*)d_in[9];
  const float* bc  = (const float*)d_in[10];
  float* out = (float*)d_out;

  const int N = in_sizes[0] / DD;   // 40000
  const int E = in_sizes[1] / 2;    // 640000
  const int G = out_size / DD;      // 64
  const int* src = ei;
  const int* dst = ei + E;

  const int Npad = (N + 64) & ~63;
  const int NB1024 = (N + 1023) / 1024;
  int* iws    = (int*)d_ws;
  int* deg    = iws;                 // Npad
  int* cursor = deg + Npad;          // Npad
  int* off    = cursor + Npad;       // Npad
  int* part   = off + Npad;
  int* total  = part + ((NB1024 + 64) & ~63);
  int* csr    = total + 64;          // E
  float* sums = (float*)(csr + E);   // G*DD
  float* cnt  = sums + (size_t)G * DD;   // 64
  unsigned short* Bpk = (unsigned short*)(cnt + 64);   // 2*64*64*8 = 65536 ushorts

  // activation buffers: rows of AS bf16 (AS=256: hi|lo, AS=128: hi only)
  unsigned short* actbase = Bpk + 65536;
  size_t fixed = (size_t)((char*)actbase - (char*)d_ws);
  int AS, has_lo;
  if (ws_size >= fixed + 3ull * N * 256 * sizeof(unsigned short)) { AS = 256; has_lo = 1; }
  else { AS = 128; has_lo = 0; }

  unsigned short* XHL = actbase;                         // N*AS
  unsigned short* AGG = XHL + (size_t)N * AS;            // N*AS
  unsigned short* H1  = AGG + (size_t)N * AS;            // N*AS
  float* h2;
  if (AS == 256) h2 = (float*)XHL;                       // x dead after gemm1; exact size match
  else           h2 = (float*)(H1 + (size_t)N * AS);     // separate 20.5 MB

  hipMemsetAsync(deg, 0, (size_t)2 * Npad * sizeof(int), stream);
  hipMemsetAsync(sums, 0, (size_t)G * DD * sizeof(float), stream);

  const int blk = 256;
  deg_kernel<<<(E + blk - 1) / blk, blk, 0, stream>>>(dst, deg, E);
  block_sum<<<NB1024, 256, 0, stream>>>(deg, part, N);
  scan_part<<<1, 256, 0, stream>>>(part, total, NB1024);
  off_kernel<<<NB1024, 1024, 0, stream>>>(deg, part, total, off, N);
  fill_csr<<<(E + blk - 1) / blk, blk, 0, stream>>>(src, dst, off, cursor, csr, E);
  wpack_kernel<<<32, 256, 0, stream>>>(Wr1, Wo1, Wr2, Wo2, Bpk);
  xsplit_kernel<<<(N * 32 + blk - 1) / blk, blk, 0, stream>>>(x, XHL, N, AS, has_lo);

  int agg_blocks = (N + ANODE - 1) / ANODE;
  int gemm_blocks = (N + 63) / 64;

  // layer 1
  gather_hl<<<agg_blocks, 256, 0, stream>>>(XHL, csr, off, deg, AGG, N, AS, has_lo);
  gemm_mfma<<<gemm_blocks, 256, 0, stream>>>(AGG, XHL, Bpk, b1, nullptr, H1, N, AS, has_lo, 1);
  // layer 2
  gather_hl<<<agg_blocks, 256, 0, stream>>>(H1, csr, off, deg, AGG, N, AS, has_lo);
  gemm_mfma<<<gemm_blocks, 256, 0, stream>>>(AGG, H1, Bpk + 32768, b2, h2, nullptr, N, AS, has_lo, 1);

  // pool + classify
  int pool_npb = 64;
  pool_kernel<<<(N + pool_npb - 1) / pool_npb, DD, 0, stream>>>(h2, batch, sums, N, pool_npb);
  cnt_kernel<<<1, 64, 0, stream>>>(batch, cnt, N, G);
  final_kernel<<<G, DD, 0, stream>>>(sums, cnt, Wc, bc, out, G);
}

// Round 7
// 209.759 us; speedup vs baseline: 14.0421x; 1.0352x over previous
//
#include <hip/hip_runtime.h>

#define DD 128
#define ANODE 4        // gather: nodes per block (1 wave per node)

typedef __attribute__((ext_vector_type(8))) short short8v;
typedef __attribute__((ext_vector_type(4))) float float4v;

static __device__ __forceinline__ unsigned short f2bf(float f) {
  unsigned int u = __float_as_uint(f);
  u = (u + 0x7fffu + ((u >> 16) & 1u)) >> 16;   // RNE
  return (unsigned short)u;
}
static __device__ __forceinline__ float bf2f(unsigned short h) {
  return __uint_as_float(((unsigned int)h) << 16);
}
static __device__ __forceinline__ float blo(unsigned int u) {
  return __uint_as_float(u << 16);
}
static __device__ __forceinline__ float bhi(unsigned int u) {
  return __uint_as_float(u & 0xffff0000u);
}

__global__ void deg_kernel(const int* __restrict__ dst, int* __restrict__ deg, int E) {
  int e = blockIdx.x * blockDim.x + threadIdx.x;
  if (e < E) atomicAdd(&deg[dst[e]], 1);
}

// ---- parallel exclusive scan of deg -> off ----
__global__ void block_sum(const int* __restrict__ deg, int* __restrict__ part, int N) {
  int base = blockIdx.x * 1024;
  int s = 0;
  for (int i = threadIdx.x; i < 1024; i += 256) {
    int idx = base + i;
    s += (idx < N) ? deg[idx] : 0;
  }
  for (int o = 32; o; o >>= 1) s += __shfl_down(s, o, 64);
  __shared__ int ws[4];
  if ((threadIdx.x & 63) == 0) ws[threadIdx.x >> 6] = s;
  __syncthreads();
  if (threadIdx.x == 0) part[blockIdx.x] = ws[0] + ws[1] + ws[2] + ws[3];
}

__global__ void scan_part(int* __restrict__ part, int* __restrict__ total, int nb) {
  __shared__ int buf[256];
  int v = (threadIdx.x < nb) ? part[threadIdx.x] : 0;
  buf[threadIdx.x] = v;
  __syncthreads();
  for (int s = 1; s < 256; s <<= 1) {
    int t = (threadIdx.x >= s) ? buf[threadIdx.x - s] : 0;
    __syncthreads();
    buf[threadIdx.x] += t;
    __syncthreads();
  }
  if (threadIdx.x < nb) part[threadIdx.x] = buf[threadIdx.x] - v;  // exclusive
  if (threadIdx.x == 255) *total = buf[255];
}

__global__ void off_kernel(const int* __restrict__ deg, const int* __restrict__ part,
                           const int* __restrict__ total, int* __restrict__ off, int N) {
  __shared__ int buf[1024];
  int i = blockIdx.x * 1024 + threadIdx.x;
  int v = (i < N) ? deg[i] : 0;
  buf[threadIdx.x] = v;
  __syncthreads();
  for (int s = 1; s < 1024; s <<= 1) {
    int t = (threadIdx.x >= s) ? buf[threadIdx.x - s] : 0;
    __syncthreads();
    buf[threadIdx.x] += t;
    __syncthreads();
  }
  if (i < N) off[i] = part[blockIdx.x] + buf[threadIdx.x] - v;
  if (blockIdx.x == 0 && threadIdx.x == 0) off[N] = *total;
}

__global__ void fill_csr(const int* __restrict__ src, const int* __restrict__ dst,
                         const int* __restrict__ off, int* __restrict__ cursor,
                         int* __restrict__ csr, int E) {
  int e = blockIdx.x * blockDim.x + threadIdx.x;
  if (e < E) {
    int d = dst[e];
    int p = atomicAdd(&cursor[d], 1);
    csr[off[d] + p] = src[e];
  }
}

// Pack W into MFMA B-fragment layout (bf16), 2 layers.
// Bpk[((L*64 + kt*8 + nt)*64 + lane)*8 + j] = Wt[kt*32+(lane>>4)*8+j][nt*16+(lane&15)]
// where Wt[k][d] = (k<128 ? Wrel[d][k] : Wroot[d][k-128]).
__global__ void wpack_kernel(const float* __restrict__ Wr1, const float* __restrict__ Wo1,
                             const float* __restrict__ Wr2, const float* __restrict__ Wo2,
                             unsigned short* __restrict__ Bpk) {
  int tid = blockIdx.x * blockDim.x + threadIdx.x;   // 8192 threads
  if (tid >= 8192) return;
  int L = tid >> 12;
  int rest = tid & 4095;
  int kt = rest >> 9;
  int nt = (rest >> 6) & 7;
  int lane = rest & 63;
  int d = nt * 16 + (lane & 15);
  int kbase = kt * 32 + (lane >> 4) * 8;
  const float* Wrel = L ? Wr2 : Wr1;
  const float* Wroot = L ? Wo2 : Wo1;
  unsigned short* o = Bpk + ((size_t)tid) * 8;
  #pragma unroll
  for (int j = 0; j < 8; ++j) {
    int k = kbase + j;
    float w = (k < DD) ? Wrel[d * DD + k] : Wroot[d * DD + (k - DD)];
    o[j] = f2bf(w);
  }
}

// x fp32 -> packed XH (hi) and XL (lo) bf16 arrays
__global__ void xsplit2(const float* __restrict__ in, unsigned short* __restrict__ XH,
                        unsigned short* __restrict__ XL, int N, int has_lo) {
  int i = blockIdx.x * blockDim.x + threadIdx.x;
  if (i >= N * 32) return;
  float4 v = reinterpret_cast<const float4*>(in)[i];
  ushort4 h;
  h.x = f2bf(v.x); h.y = f2bf(v.y); h.z = f2bf(v.z); h.w = f2bf(v.w);
  reinterpret_cast<ushort4*>(XH)[i] = h;
  if (has_lo) {
    ushort4 l;
    l.x = f2bf(v.x - bf2f(h.x)); l.y = f2bf(v.y - bf2f(h.y));
    l.z = f2bf(v.z - bf2f(h.z)); l.w = f2bf(v.w - bf2f(h.w));
    reinterpret_cast<ushort4*>(XL)[i] = l;
  }
}

// AGG[n] = mean_{j in N(n)} X[j], reading packed hi rows (256B); emits packed hi/lo.
// 1 wave per node, 8 neighbor rows in flight.
__global__ __launch_bounds__(256) void gather2(
    const unsigned int* __restrict__ X32, const int* __restrict__ csr,
    const int* __restrict__ off, const int* __restrict__ deg,
    unsigned int* __restrict__ AH32, unsigned int* __restrict__ AL32,
    int N, int has_lo) {
  int node = blockIdx.x * ANODE + (threadIdx.x >> 6);
  if (node >= N) return;
  int lane = threadIdx.x & 63;
  int p = off[node];
  int dg = deg[node];
  int pe = p + dg;
  float ax = 0.f, ay = 0.f;
  for (; p + 8 <= pe; p += 8) {
    int s0 = csr[p + 0], s1 = csr[p + 1], s2 = csr[p + 2], s3 = csr[p + 3];
    int s4 = csr[p + 4], s5 = csr[p + 5], s6 = csr[p + 6], s7 = csr[p + 7];
    unsigned int u0 = X32[(size_t)s0 * 64 + lane];
    unsigned int u1 = X32[(size_t)s1 * 64 + lane];
    unsigned int u2 = X32[(size_t)s2 * 64 + lane];
    unsigned int u3 = X32[(size_t)s3 * 64 + lane];
    unsigned int u4 = X32[(size_t)s4 * 64 + lane];
    unsigned int u5 = X32[(size_t)s5 * 64 + lane];
    unsigned int u6 = X32[(size_t)s6 * 64 + lane];
    unsigned int u7 = X32[(size_t)s7 * 64 + lane];
    ax += (blo(u0) + blo(u1)) + (blo(u2) + blo(u3)) + (blo(u4) + blo(u5)) + (blo(u6) + blo(u7));
    ay += (bhi(u0) + bhi(u1)) + (bhi(u2) + bhi(u3)) + (bhi(u4) + bhi(u5)) + (bhi(u6) + bhi(u7));
  }
  for (; p < pe; ++p) {
    unsigned int u = X32[(size_t)csr[p] * 64 + lane];
    ax += blo(u); ay += bhi(u);
  }
  float inv = 1.f / fmaxf((float)dg, 1.f);
  ax *= inv; ay *= inv;
  unsigned short hx = f2bf(ax), hy = f2bf(ay);
  AH32[(size_t)node * 64 + lane] = (unsigned int)hx | ((unsigned int)hy << 16);
  if (has_lo) {
    unsigned short lx = f2bf(ax - bf2f(hx)), ly = f2bf(ay - bf2f(hy));
    AL32[(size_t)node * 64 + lane] = (unsigned int)lx | ((unsigned int)ly << 16);
  }
}

// H = relu([AGG|X] @ Wcat + b) via MFMA (split-activation fp32 fidelity).
// If sums!=null: fused mean-pool epilogue (no H materialization); else write HH/HL.
__global__ __launch_bounds__(256) void gemm2(
    const unsigned short* __restrict__ AH, const unsigned short* __restrict__ AL,
    const unsigned short* __restrict__ XH, const unsigned short* __restrict__ XL,
    const unsigned short* __restrict__ Bpk, const float* __restrict__ bias,
    unsigned short* __restrict__ HH, unsigned short* __restrict__ HL,
    float* __restrict__ sums, const int* __restrict__ batch,
    int N, int has_lo) {
  int lane = threadIdx.x & 63;
  int wid = threadIdx.x >> 6;
  int m0 = (blockIdx.x * 4 + wid) * 16;
  if (m0 >= N) return;
  int arow = m0 + (lane & 15);
  if (arow >= N) arow = N - 1;
  int koff = (lane >> 4) * 8;
  const short8v* Bf = (const short8v*)Bpk;
  float4v acc[8];
  #pragma unroll
  for (int nt = 0; nt < 8; ++nt) acc[nt] = (float4v){0.f, 0.f, 0.f, 0.f};

  #pragma unroll
  for (int kt = 0; kt < 8; ++kt) {
    const unsigned short* hb = (kt < 4)
        ? (AH + (size_t)arow * DD + kt * 32 + koff)
        : (XH + (size_t)arow * DD + (kt - 4) * 32 + koff);
    short8v ahi = *reinterpret_cast<const short8v*>(hb);
    if (has_lo) {
      const unsigned short* lb = (kt < 4)
          ? (AL + (size_t)arow * DD + kt * 32 + koff)
          : (XL + (size_t)arow * DD + (kt - 4) * 32 + koff);
      short8v alo = *reinterpret_cast<const short8v*>(lb);
      #pragma unroll
      for (int nt = 0; nt < 8; ++nt) {
        short8v b = Bf[(kt * 8 + nt) * 64 + lane];
        acc[nt] = __builtin_amdgcn_mfma_f32_16x16x32_bf16(ahi, b, acc[nt], 0, 0, 0);
        acc[nt] = __builtin_amdgcn_mfma_f32_16x16x32_bf16(alo, b, acc[nt], 0, 0, 0);
      }
    } else {
      #pragma unroll
      for (int nt = 0; nt < 8; ++nt) {
        short8v b = Bf[(kt * 8 + nt) * 64 + lane];
        acc[nt] = __builtin_amdgcn_mfma_f32_16x16x32_bf16(ahi, b, acc[nt], 0, 0, 0);
      }
    }
  }

  int col0 = lane & 15;
  int rbase = m0 + (lane >> 4) * 4;
  if (sums) {
    // fused global-mean-pool: batch is sorted; one-graph tiles take the fast path
    int gl = batch[m0];
    int me = (m0 + 15 < N) ? m0 + 15 : N - 1;
    int gh = batch[me];
    bool fast = (gl == gh) && (m0 + 16 <= N);
    #pragma unroll
    for (int nt = 0; nt < 8; ++nt) {
      int col = nt * 16 + col0;
      float bv = bias[col];
      float v0 = fmaxf(acc[nt][0] + bv, 0.f);
      float v1 = fmaxf(acc[nt][1] + bv, 0.f);
      float v2 = fmaxf(acc[nt][2] + bv, 0.f);
      float v3 = fmaxf(acc[nt][3] + bv, 0.f);
      if (fast) {
        float s = (v0 + v1) + (v2 + v3);
        s += __shfl_xor(s, 16, 64);
        s += __shfl_xor(s, 32, 64);
        if (lane < 16) atomicAdd(&sums[gl * DD + col], s);
      } else {
        float vv[4] = {v0, v1, v2, v3};
        #pragma unroll
        for (int r = 0; r < 4; ++r) {
          int row = rbase + r;
          if (row < N) atomicAdd(&sums[batch[row] * DD + col], vv[r]);
        }
      }
    }
  } else {
    #pragma unroll
    for (int nt = 0; nt < 8; ++nt) {
      int col = nt * 16 + col0;
      float bv = bias[col];
      #pragma unroll
      for (int r = 0; r < 4; ++r) {
        int row = rbase + r;
        if (row < N) {
          float v = fmaxf(acc[nt][r] + bv, 0.f);
          unsigned short h = f2bf(v);
          HH[(size_t)row * DD + col] = h;
          if (has_lo) HL[(size_t)row * DD + col] = f2bf(v - bf2f(h));
        }
      }
    }
  }
}

// batch sorted -> cnt[g] via binary search, no atomics
__global__ void cnt_kernel(const int* __restrict__ batch, float* __restrict__ cnt,
                           int N, int G) {
  int g = blockIdx.x * blockDim.x + threadIdx.x;
  if (g >= G) return;
  int lo = 0, hi = N;
  while (lo < hi) { int m = (lo + hi) >> 1; if (batch[m] < g) lo = m + 1; else hi = m; }
  int a = lo;
  lo = 0; hi = N;
  while (lo < hi) { int m = (lo + hi) >> 1; if (batch[m] < g + 1) lo = m + 1; else hi = m; }
  cnt[g] = (float)(lo - a);
}

__global__ void final_kernel(const float* __restrict__ sums, const float* __restrict__ cnt,
                             const float* __restrict__ Wc, const float* __restrict__ bc,
                             float* __restrict__ out, int G) {
  int g = blockIdx.x;
  int d = threadIdx.x;
  __shared__ float p[DD];
  float inv = 1.0f / fmaxf(cnt[g], 1.0f);
  p[d] = sums[g * DD + d] * inv;
  __syncthreads();
  float acc = bc[d];
  #pragma unroll 8
  for (int k = 0; k < DD; ++k) acc += p[k] * Wc[d * DD + k];
  out[g * DD + d] = acc;
}

extern "C" void kernel_launch(void* const* d_in, const int* in_sizes, int n_in,
                              void* d_out, int out_size, void* d_ws, size_t ws_size,
                              hipStream_t stream) {
  const float* x   = (const float*)d_in[0];
  const int*   ei  = (const int*)d_in[1];
  const int* batch = (const int*)d_in[2];
  const float* Wr1 = (const float*)d_in[3];
  const float* Wo1 = (const float*)d_in[4];
  const float* b1  = (const float*)d_in[5];
  const float* Wr2 = (const float*)d_in[6];
  const float* Wo2 = (const float*)d_in[7];
  const float* b2  = (const float*)d_in[8];
  const float* Wc  = (const float*)d_in[9];
  const float* bc  = (const float*)d_in[10];
  float* out = (float*)d_out;

  const int N = in_sizes[0] / DD;   // 40000
  const int E = in_sizes[1] / 2;    // 640000
  const int G = out_size / DD;      // 64
  const int* src = ei;
  const int* dst = ei + E;

  const int Npad = (N + 64) & ~63;
  const int NB1024 = (N + 1023) / 1024;
  int* iws    = (int*)d_ws;
  int* deg    = iws;                 // Npad
  int* cursor = deg + Npad;          // Npad
  int* off    = cursor + Npad;       // Npad
  int* part   = off + Npad;
  int* total  = part + ((NB1024 + 64) & ~63);
  int* csr    = total + 64;          // E
  float* sums = (float*)(csr + E);   // G*DD
  float* cnt  = sums + (size_t)G * DD;   // 64
  unsigned short* Bpk = (unsigned short*)(cnt + 64);   // 65536 ushorts

  unsigned short* actbase = Bpk + 65536;
  size_t fixed = (size_t)((char*)actbase - (char*)d_ws);
  size_t arr = (size_t)N * DD * sizeof(unsigned short);
  int has_lo = (ws_size >= fixed + 6 * arr) ? 1 : 0;

  unsigned short* XH = actbase;               // N*DD
  unsigned short* AH = XH + (size_t)N * DD;   // N*DD
  unsigned short* HH = AH + (size_t)N * DD;   // N*DD
  unsigned short* XL = has_lo ? HH + (size_t)N * DD : nullptr;
  unsigned short* AL = has_lo ? XL + (size_t)N * DD : nullptr;
  unsigned short* HL = has_lo ? AL + (size_t)N * DD : nullptr;

  hipMemsetAsync(deg, 0, (size_t)2 * Npad * sizeof(int), stream);
  hipMemsetAsync(sums, 0, (size_t)G * DD * sizeof(float), stream);

  const int blk = 256;
  deg_kernel<<<(E + blk - 1) / blk, blk, 0, stream>>>(dst, deg, E);
  block_sum<<<NB1024, 256, 0, stream>>>(deg, part, N);
  scan_part<<<1, 256, 0, stream>>>(part, total, NB1024);
  off_kernel<<<NB1024, 1024, 0, stream>>>(deg, part, total, off, N);
  fill_csr<<<(E + blk - 1) / blk, blk, 0, stream>>>(src, dst, off, cursor, csr, E);
  wpack_kernel<<<32, 256, 0, stream>>>(Wr1, Wo1, Wr2, Wo2, Bpk);
  xsplit2<<<(N * 32 + blk - 1) / blk, blk, 0, stream>>>(x, XH, XL, N, has_lo);

  int agg_blocks = (N + ANODE - 1) / ANODE;
  int gemm_blocks = (N + 63) / 64;

  // layer 1: gather(XH) -> AGG; H1 = relu([AGG|X]W1+b1) stored hi/lo
  gather2<<<agg_blocks, 256, 0, stream>>>((const unsigned int*)XH, csr, off, deg,
                                          (unsigned int*)AH, (unsigned int*)AL, N, has_lo);
  gemm2<<<gemm_blocks, 256, 0, stream>>>(AH, AL, XH, XL, Bpk, b1,
                                         HH, HL, nullptr, nullptr, N, has_lo);
  // layer 2: gather(HH) -> AGG; pooled sums += relu([AGG|H1]W2+b2)
  gather2<<<agg_blocks, 256, 0, stream>>>((const unsigned int*)HH, csr, off, deg,
                                          (unsigned int*)AH, (unsigned int*)AL, N, has_lo);
  gemm2<<<gemm_blocks, 256, 0, stream>>>(AH, AL, HH, HL, Bpk + 32768, b2,
                                         nullptr, nullptr, sums, batch, N, has_lo);

  cnt_kernel<<<1, 64, 0, stream>>>(batch, cnt, N, G);
  final_kernel<<<G, DD, 0, stream>>>(sums, cnt, Wc, bc, out, G);
}

// Round 8
// 195.171 us; speedup vs baseline: 15.0917x; 1.0747x over previous
//
#include <hip/hip_runtime.h>

#define DD 128
#define ANODE 4        // gather: nodes per block (1 wave per node)

typedef __attribute__((ext_vector_type(8))) short short8v;
typedef __attribute__((ext_vector_type(4))) float float4v;

static __device__ __forceinline__ unsigned short f2bf(float f) {
  unsigned int u = __float_as_uint(f);
  u = (u + 0x7fffu + ((u >> 16) & 1u)) >> 16;   // RNE
  return (unsigned short)u;
}
static __device__ __forceinline__ float bf2f(unsigned short h) {
  return __uint_as_float(((unsigned int)h) << 16);
}
static __device__ __forceinline__ float blo(unsigned int u) {
  return __uint_as_float(u << 16);
}
static __device__ __forceinline__ float bhi(unsigned int u) {
  return __uint_as_float(u & 0xffff0000u);
}
static __device__ __forceinline__ unsigned int pk(float lo, float hi) {
  return (unsigned int)f2bf(lo) | ((unsigned int)f2bf(hi) << 16);
}

__global__ void zero_kernel(int* __restrict__ deg, float* __restrict__ sums,
                            int ndeg, int nsums) {
  int i = blockIdx.x * blockDim.x + threadIdx.x;
  if (i < ndeg) deg[i] = 0;
  if (i < nsums) sums[i] = 0.f;
}

__global__ void deg_kernel(const int* __restrict__ dst, int* __restrict__ deg, int E) {
  int e = blockIdx.x * blockDim.x + threadIdx.x;
  if (e < E) atomicAdd(&deg[dst[e]], 1);
}

// ---- parallel exclusive scan of deg -> off ----
__global__ void block_sum(const int* __restrict__ deg, int* __restrict__ part, int N) {
  int base = blockIdx.x * 1024;
  int s = 0;
  for (int i = threadIdx.x; i < 1024; i += 256) {
    int idx = base + i;
    s += (idx < N) ? deg[idx] : 0;
  }
  for (int o = 32; o; o >>= 1) s += __shfl_down(s, o, 64);
  __shared__ int ws[4];
  if ((threadIdx.x & 63) == 0) ws[threadIdx.x >> 6] = s;
  __syncthreads();
  if (threadIdx.x == 0) part[blockIdx.x] = ws[0] + ws[1] + ws[2] + ws[3];
}

__global__ void scan_part(int* __restrict__ part, int* __restrict__ total, int nb) {
  __shared__ int buf[256];
  int v = (threadIdx.x < nb) ? part[threadIdx.x] : 0;
  buf[threadIdx.x] = v;
  __syncthreads();
  for (int s = 1; s < 256; s <<= 1) {
    int t = (threadIdx.x >= s) ? buf[threadIdx.x - s] : 0;
    __syncthreads();
    buf[threadIdx.x] += t;
    __syncthreads();
  }
  if (threadIdx.x < nb) part[threadIdx.x] = buf[threadIdx.x] - v;  // exclusive
  if (threadIdx.x == 255) *total = buf[255];
}

__global__ void off_kernel(const int* __restrict__ deg, const int* __restrict__ part,
                           const int* __restrict__ total, int* __restrict__ off, int N) {
  __shared__ int buf[1024];
  int i = blockIdx.x * 1024 + threadIdx.x;
  int v = (i < N) ? deg[i] : 0;
  buf[threadIdx.x] = v;
  __syncthreads();
  for (int s = 1; s < 1024; s <<= 1) {
    int t = (threadIdx.x >= s) ? buf[threadIdx.x - s] : 0;
    __syncthreads();
    buf[threadIdx.x] += t;
    __syncthreads();
  }
  if (i < N) off[i] = part[blockIdx.x] + buf[threadIdx.x] - v;
  if (blockIdx.x == 0 && threadIdx.x == 0) off[N] = *total;
}

// deg doubles as cursor (atomicSub); deg is dead afterwards (gather uses off diffs)
__global__ void fill_csr(const int* __restrict__ src, const int* __restrict__ dst,
                         const int* __restrict__ off, int* __restrict__ deg,
                         unsigned short* __restrict__ csr, int E) {
  int e = blockIdx.x * blockDim.x + threadIdx.x;
  if (e < E) {
    int d = dst[e];
    int p = atomicSub(&deg[d], 1) - 1;
    csr[off[d] + p] = (unsigned short)src[e];
  }
}

// Pack W into MFMA B-fragment layout (bf16), 2 layers.
__global__ void wpack_kernel(const float* __restrict__ Wr1, const float* __restrict__ Wo1,
                             const float* __restrict__ Wr2, const float* __restrict__ Wo2,
                             unsigned short* __restrict__ Bpk) {
  int tid = blockIdx.x * blockDim.x + threadIdx.x;   // 8192 threads
  if (tid >= 8192) return;
  int L = tid >> 12;
  int rest = tid & 4095;
  int kt = rest >> 9;
  int nt = (rest >> 6) & 7;
  int lane = rest & 63;
  int d = nt * 16 + (lane & 15);
  int kbase = kt * 32 + (lane >> 4) * 8;
  const float* Wrel = L ? Wr2 : Wr1;
  const float* Wroot = L ? Wo2 : Wo1;
  unsigned short* o = Bpk + ((size_t)tid) * 8;
  #pragma unroll
  for (int j = 0; j < 8; ++j) {
    int k = kbase + j;
    float w = (k < DD) ? Wrel[d * DD + k] : Wroot[d * DD + (k - DD)];
    o[j] = f2bf(w);
  }
}

// x fp32 -> packed XH (hi) and XL (lo) bf16 arrays
__global__ void xsplit2(const float* __restrict__ in, unsigned short* __restrict__ XH,
                        unsigned short* __restrict__ XL, int N, int has_lo) {
  int i = blockIdx.x * blockDim.x + threadIdx.x;
  if (i >= N * 32) return;
  float4 v = reinterpret_cast<const float4*>(in)[i];
  ushort4 h;
  h.x = f2bf(v.x); h.y = f2bf(v.y); h.z = f2bf(v.z); h.w = f2bf(v.w);
  reinterpret_cast<ushort4*>(XH)[i] = h;
  if (has_lo) {
    ushort4 l;
    l.x = f2bf(v.x - bf2f(h.x)); l.y = f2bf(v.y - bf2f(h.y));
    l.z = f2bf(v.z - bf2f(h.z)); l.w = f2bf(v.w - bf2f(h.w));
    reinterpret_cast<ushort4*>(XL)[i] = l;
  }
}

// AGG[n] = mean_{j in N(n)} X[j]: 1 wave/node, 4 rows in parallel
// (16 lanes x dwordx4 each), 8 neighbors in flight.
__global__ __launch_bounds__(256) void gather3(
    const uint4* __restrict__ X4, const unsigned short* __restrict__ csr,
    const int* __restrict__ off,
    uint4* __restrict__ AH4, uint4* __restrict__ AL4,
    int N, int has_lo) {
  int node = blockIdx.x * ANODE + (threadIdx.x >> 6);
  if (node >= N) return;
  int lane = threadIdx.x & 63;
  int sub = lane >> 4;       // neighbor slot 0..3
  int sl = lane & 15;        // 16B chunk within row
  int p0 = off[node];
  int pe = off[node + 1];
  int dg = pe - p0;
  float a0 = 0.f, a1 = 0.f, a2 = 0.f, a3 = 0.f, a4 = 0.f, a5 = 0.f, a6 = 0.f, a7 = 0.f;
  int p = p0;
  for (; p + 8 <= pe; p += 8) {
    int s0 = csr[p + sub];
    int s1 = csr[p + 4 + sub];
    uint4 u0 = X4[(size_t)s0 * 16 + sl];
    uint4 u1 = X4[(size_t)s1 * 16 + sl];
    a0 += blo(u0.x) + blo(u1.x);  a1 += bhi(u0.x) + bhi(u1.x);
    a2 += blo(u0.y) + blo(u1.y);  a3 += bhi(u0.y) + bhi(u1.y);
    a4 += blo(u0.z) + blo(u1.z);  a5 += bhi(u0.z) + bhi(u1.z);
    a6 += blo(u0.w) + blo(u1.w);  a7 += bhi(u0.w) + bhi(u1.w);
  }
  for (; p < pe; p += 4) {
    int q = p + sub;
    bool act = q < pe;
    int s0 = act ? (int)csr[q] : 0;
    uint4 u0 = X4[(size_t)s0 * 16 + sl];
    if (act) {
      a0 += blo(u0.x); a1 += bhi(u0.x);
      a2 += blo(u0.y); a3 += bhi(u0.y);
      a4 += blo(u0.z); a5 += bhi(u0.z);
      a6 += blo(u0.w); a7 += bhi(u0.w);
    }
  }
  #define RED2(v) v += __shfl_xor(v, 16, 64); v += __shfl_xor(v, 32, 64);
  RED2(a0) RED2(a1) RED2(a2) RED2(a3) RED2(a4) RED2(a5) RED2(a6) RED2(a7)
  #undef RED2
  float inv = 1.f / fmaxf((float)dg, 1.f);
  a0 *= inv; a1 *= inv; a2 *= inv; a3 *= inv;
  a4 *= inv; a5 *= inv; a6 *= inv; a7 *= inv;
  if (sub == 0) {
    uint4 h;
    h.x = pk(a0, a1); h.y = pk(a2, a3); h.z = pk(a4, a5); h.w = pk(a6, a7);
    AH4[(size_t)node * 16 + sl] = h;
    if (has_lo) {
      uint4 l;
      l.x = pk(a0 - bf2f((unsigned short)(h.x & 0xffff)), a1 - bf2f((unsigned short)(h.x >> 16)));
      l.y = pk(a2 - bf2f((unsigned short)(h.y & 0xffff)), a3 - bf2f((unsigned short)(h.y >> 16)));
      l.z = pk(a4 - bf2f((unsigned short)(h.z & 0xffff)), a5 - bf2f((unsigned short)(h.z >> 16)));
      l.w = pk(a6 - bf2f((unsigned short)(h.w & 0xffff)), a7 - bf2f((unsigned short)(h.w >> 16)));
      AL4[(size_t)node * 16 + sl] = l;
    }
  }
}

// H = relu([AGG|X] @ Wcat + b) via MFMA (split-activation fp32 fidelity).
// If sums!=null: fused mean-pool epilogue; else write HH/HL.
__global__ __launch_bounds__(256) void gemm2(
    const unsigned short* __restrict__ AH, const unsigned short* __restrict__ AL,
    const unsigned short* __restrict__ XH, const unsigned short* __restrict__ XL,
    const unsigned short* __restrict__ Bpk, const float* __restrict__ bias,
    unsigned short* __restrict__ HH, unsigned short* __restrict__ HL,
    float* __restrict__ sums, const int* __restrict__ batch,
    int N, int has_lo) {
  int lane = threadIdx.x & 63;
  int wid = threadIdx.x >> 6;
  int m0 = (blockIdx.x * 4 + wid) * 16;
  if (m0 >= N) return;
  int arow = m0 + (lane & 15);
  if (arow >= N) arow = N - 1;
  int koff = (lane >> 4) * 8;
  const short8v* Bf = (const short8v*)Bpk;
  float4v acc[8];
  #pragma unroll
  for (int nt = 0; nt < 8; ++nt) acc[nt] = (float4v){0.f, 0.f, 0.f, 0.f};

  #pragma unroll
  for (int kt = 0; kt < 8; ++kt) {
    const unsigned short* hb = (kt < 4)
        ? (AH + (size_t)arow * DD + kt * 32 + koff)
        : (XH + (size_t)arow * DD + (kt - 4) * 32 + koff);
    short8v ahi = *reinterpret_cast<const short8v*>(hb);
    if (has_lo) {
      const unsigned short* lb = (kt < 4)
          ? (AL + (size_t)arow * DD + kt * 32 + koff)
          : (XL + (size_t)arow * DD + (kt - 4) * 32 + koff);
      short8v alo = *reinterpret_cast<const short8v*>(lb);
      #pragma unroll
      for (int nt = 0; nt < 8; ++nt) {
        short8v b = Bf[(kt * 8 + nt) * 64 + lane];
        acc[nt] = __builtin_amdgcn_mfma_f32_16x16x32_bf16(ahi, b, acc[nt], 0, 0, 0);
        acc[nt] = __builtin_amdgcn_mfma_f32_16x16x32_bf16(alo, b, acc[nt], 0, 0, 0);
      }
    } else {
      #pragma unroll
      for (int nt = 0; nt < 8; ++nt) {
        short8v b = Bf[(kt * 8 + nt) * 64 + lane];
        acc[nt] = __builtin_amdgcn_mfma_f32_16x16x32_bf16(ahi, b, acc[nt], 0, 0, 0);
      }
    }
  }

  int col0 = lane & 15;
  int rbase = m0 + (lane >> 4) * 4;
  if (sums) {
    int gl = batch[m0];
    int me = (m0 + 15 < N) ? m0 + 15 : N - 1;
    int gh = batch[me];
    bool fast = (gl == gh) && (m0 + 16 <= N);
    #pragma unroll
    for (int nt = 0; nt < 8; ++nt) {
      int col = nt * 16 + col0;
      float bv = bias[col];
      float v0 = fmaxf(acc[nt][0] + bv, 0.f);
      float v1 = fmaxf(acc[nt][1] + bv, 0.f);
      float v2 = fmaxf(acc[nt][2] + bv, 0.f);
      float v3 = fmaxf(acc[nt][3] + bv, 0.f);
      if (fast) {
        float s = (v0 + v1) + (v2 + v3);
        s += __shfl_xor(s, 16, 64);
        s += __shfl_xor(s, 32, 64);
        if (lane < 16) atomicAdd(&sums[gl * DD + col], s);
      } else {
        float vv[4] = {v0, v1, v2, v3};
        #pragma unroll
        for (int r = 0; r < 4; ++r) {
          int row = rbase + r;
          if (row < N) atomicAdd(&sums[batch[row] * DD + col], vv[r]);
        }
      }
    }
  } else {
    #pragma unroll
    for (int nt = 0; nt < 8; ++nt) {
      int col = nt * 16 + col0;
      float bv = bias[col];
      #pragma unroll
      for (int r = 0; r < 4; ++r) {
        int row = rbase + r;
        if (row < N) {
          float v = fmaxf(acc[nt][r] + bv, 0.f);
          unsigned short h = f2bf(v);
          HH[(size_t)row * DD + col] = h;
          if (has_lo) HL[(size_t)row * DD + col] = f2bf(v - bf2f(h));
        }
      }
    }
  }
}

// out[g] = (sums[g]/cnt[g]) @ Wc^T + bc ; cnt via binary search (batch sorted)
__global__ void final_kernel(const float* __restrict__ sums, const int* __restrict__ batch,
                             const float* __restrict__ Wc, const float* __restrict__ bc,
                             float* __restrict__ out, int N, int G) {
  int g = blockIdx.x;
  int d = threadIdx.x;
  __shared__ float p[DD];
  __shared__ float invs;
  if (d == 0) {
    int lo = 0, hi = N;
    while (lo < hi) { int m = (lo + hi) >> 1; if (batch[m] < g) lo = m + 1; else hi = m; }
    int a = lo;
    lo = 0; hi = N;
    while (lo < hi) { int m = (lo + hi) >> 1; if (batch[m] < g + 1) lo = m + 1; else hi = m; }
    invs = 1.0f / fmaxf((float)(lo - a), 1.0f);
  }
  __syncthreads();
  p[d] = sums[g * DD + d] * invs;
  __syncthreads();
  float acc = bc[d];
  #pragma unroll 8
  for (int k = 0; k < DD; ++k) acc += p[k] * Wc[d * DD + k];
  out[g * DD + d] = acc;
}

extern "C" void kernel_launch(void* const* d_in, const int* in_sizes, int n_in,
                              void* d_out, int out_size, void* d_ws, size_t ws_size,
                              hipStream_t stream) {
  const float* x   = (const float*)d_in[0];
  const int*   ei  = (const int*)d_in[1];
  const int* batch = (const int*)d_in[2];
  const float* Wr1 = (const float*)d_in[3];
  const float* Wo1 = (const float*)d_in[4];
  const float* b1  = (const float*)d_in[5];
  const float* Wr2 = (const float*)d_in[6];
  const float* Wo2 = (const float*)d_in[7];
  const float* b2  = (const float*)d_in[8];
  const float* Wc  = (const float*)d_in[9];
  const float* bc  = (const float*)d_in[10];
  float* out = (float*)d_out;

  const int N = in_sizes[0] / DD;   // 40000
  const int E = in_sizes[1] / 2;    // 640000
  const int G = out_size / DD;      // 64
  const int* src = ei;
  const int* dst = ei + E;

  const int Npad = (N + 64) & ~63;
  const int NB1024 = (N + 1023) / 1024;
  int* iws    = (int*)d_ws;
  int* deg    = iws;                 // Npad (also cursor)
  int* off    = deg + Npad;          // Npad (>= N+1)
  int* part   = off + Npad;          // 64
  int* total  = part + 64;           // 64
  unsigned short* csr = (unsigned short*)(total + 64);   // E u16
  float* sums = (float*)(csr + ((E + 7) & ~7));          // G*DD
  unsigned short* Bpk = (unsigned short*)(sums + (size_t)G * DD);  // 65536

  unsigned short* actbase = Bpk + 65536;
  size_t fixed = (size_t)((char*)actbase - (char*)d_ws);
  size_t arr = (size_t)N * DD * sizeof(unsigned short);
  int has_lo = (ws_size >= fixed + 6 * arr) ? 1 : 0;

  unsigned short* XH = actbase;               // N*DD
  unsigned short* AH = XH + (size_t)N * DD;   // N*DD
  unsigned short* HH = AH + (size_t)N * DD;   // N*DD
  unsigned short* XL = has_lo ? HH + (size_t)N * DD : nullptr;
  unsigned short* AL = has_lo ? XL + (size_t)N * DD : nullptr;
  unsigned short* HL = has_lo ? AL + (size_t)N * DD : nullptr;

  const int blk = 256;
  int zn = (Npad > G * DD) ? Npad : G * DD;
  zero_kernel<<<(zn + blk - 1) / blk, blk, 0, stream>>>(deg, sums, Npad, G * DD);
  deg_kernel<<<(E + blk - 1) / blk, blk, 0, stream>>>(dst, deg, E);
  block_sum<<<NB1024, 256, 0, stream>>>(deg, part, N);
  scan_part<<<1, 256, 0, stream>>>(part, total, NB1024);
  off_kernel<<<NB1024, 1024, 0, stream>>>(deg, part, total, off, N);
  fill_csr<<<(E + blk - 1) / blk, blk, 0, stream>>>(src, dst, off, deg, csr, E);
  wpack_kernel<<<32, 256, 0, stream>>>(Wr1, Wo1, Wr2, Wo2, Bpk);
  xsplit2<<<(N * 32 + blk - 1) / blk, blk, 0, stream>>>(x, XH, XL, N, has_lo);

  int agg_blocks = (N + ANODE - 1) / ANODE;
  int gemm_blocks = (N + 63) / 64;

  // layer 1: gather(XH) -> AGG; H1 = relu([AGG|X]W1+b1) stored hi/lo
  gather3<<<agg_blocks, 256, 0, stream>>>((const uint4*)XH, csr, off,
                                          (uint4*)AH, (uint4*)AL, N, has_lo);
  gemm2<<<gemm_blocks, 256, 0, stream>>>(AH, AL, XH, XL, Bpk, b1,
                                         HH, HL, nullptr, nullptr, N, has_lo);
  // layer 2: gather(HH) -> AGG; pooled sums += relu([AGG|H1]W2+b2)
  gather3<<<agg_blocks, 256, 0, stream>>>((const uint4*)HH, csr, off,
                                          (uint4*)AH, (uint4*)AL, N, has_lo);
  gemm2<<<gemm_blocks, 256, 0, stream>>>(AH, AL, HH, HL, Bpk + 32768, b2,
                                         nullptr, nullptr, sums, batch, N, has_lo);

  final_kernel<<<G, DD, 0, stream>>>(sums, batch, Wc, bc, out, N, G);
}